// Round 10
// baseline (856.180 us; speedup 1.0000x reference)
//
#include <hip/hip_runtime.h>
#include <hip/hip_bf16.h>
#include <hip/hip_cooperative_groups.h>

namespace cg = cooperative_groups;

#define N_NODES 50000
#define N_EDGES 800000
#define ETOT    (N_EDGES + N_NODES)
#define NB      64
#define IN_C    128
#define HID     64
#define HEADS   4
#define F1      (HEADS * HID)   /* 256 */
#define NEG     0.2f
#define SCAN_NBLK ((N_NODES + 255) / 256)   /* 196 */
#define PREP_BLOCKS 1024

typedef __attribute__((ext_vector_type(8))) short  short8v;
typedef __attribute__((ext_vector_type(4))) float  float4v;

__device__ __forceinline__ float lrelu(float x) { return x >= 0.f ? x : NEG * x; }

// round-to-nearest-even f32 -> bf16 bits
__device__ __forceinline__ unsigned short f2bf(float f) {
    unsigned u = __float_as_uint(f);
    u += 0x7FFFu + ((u >> 16) & 1u);
    return (unsigned short)(u >> 16);
}
__device__ __forceinline__ float bf2f(unsigned short h) {
    return __uint_as_float(((unsigned)h) << 16);
}

// ---------------- fused preprocessing: zero+convw | deg | scan | scatter ----------------
__global__ void prep_kernel(const int* __restrict__ ei,
                            const float* __restrict__ W1, const float* __restrict__ W2,
                            int* __restrict__ deg, int* __restrict__ off,
                            int* __restrict__ part, int* __restrict__ esrc,
                            unsigned short* __restrict__ W1h, unsigned short* __restrict__ W1l,
                            unsigned short* __restrict__ W2h, unsigned short* __restrict__ W2l) {
    cg::grid_group grid = cg::this_grid();
    __shared__ int sh[256];
    int t   = threadIdx.x;
    int tid = blockIdx.x * 256 + t;
    const int NT = PREP_BLOCKS * 256;

    // phase 0: zero deg + convert both W
    for (int i = tid; i < N_NODES; i += NT) deg[i] = 0;
    {
        const int N1 = IN_C * 256;
        for (int i = tid; i < N1 + F1 * 256; i += NT) {
            if (i < N1) {
                int k = i >> 8, n = i & 255;
                float v = W1[i];
                unsigned short h = f2bf(v);
                W1h[n * IN_C + k] = h;
                W1l[n * IN_C + k] = f2bf(v - bf2f(h));
            } else {
                int j = i - N1;
                int k = j >> 8, n = j & 255;
                float v = W2[j];
                unsigned short h = f2bf(v);
                W2h[n * F1 + k] = h;
                W2l[n * F1 + k] = f2bf(v - bf2f(h));
            }
        }
    }
    grid.sync();

    // phase 1: degree count
    for (int e = tid; e < ETOT; e += NT) {
        int d = (e < N_EDGES) ? ei[N_EDGES + e] : (e - N_EDGES);
        atomicAdd(&deg[d], 1);
    }
    grid.sync();

    // phase 2: per-block partial sums (blocks 0..SCAN_NBLK-1)
    if (blockIdx.x < SCAN_NBLK) {
        int i = blockIdx.x * 256 + t;
        sh[t] = (i < N_NODES) ? deg[i] : 0;
        __syncthreads();
        #pragma unroll
        for (int o = 128; o; o >>= 1) {
            if (t < o) sh[t] += sh[t + o];
            __syncthreads();
        }
        if (t == 0) part[blockIdx.x] = sh[0];
    }
    grid.sync();

    // phase 3: scan of partials (block 0)
    if (blockIdx.x == 0) {
        int v = (t < SCAN_NBLK) ? part[t] : 0;
        sh[t] = v;
        __syncthreads();
        #pragma unroll
        for (int o = 1; o < 256; o <<= 1) {
            int u = (t >= o) ? sh[t - o] : 0;
            __syncthreads();
            sh[t] += u;
            __syncthreads();
        }
        if (t < SCAN_NBLK) part[t] = sh[t] - v;   // exclusive block base
        if (t == 255) off[N_NODES] = sh[255];
    }
    grid.sync();

    // phase 4: in-block exclusive scan + base; reset deg as cursor
    if (blockIdx.x < SCAN_NBLK) {
        int i = blockIdx.x * 256 + t;
        int v = (i < N_NODES) ? deg[i] : 0;
        sh[t] = v;
        __syncthreads();
        #pragma unroll
        for (int o = 1; o < 256; o <<= 1) {
            int u = (t >= o) ? sh[t - o] : 0;
            __syncthreads();
            sh[t] += u;
            __syncthreads();
        }
        if (i < N_NODES) {
            off[i] = part[blockIdx.x] + sh[t] - v;
            deg[i] = 0;
        }
    }
    grid.sync();

    // phase 5: scatter
    for (int e = tid; e < ETOT; e += NT) {
        int s, d;
        if (e < N_EDGES) { s = ei[e]; d = ei[N_EDGES + e]; }
        else             { s = d = e - N_EDGES; }
        int pos = off[d] + atomicAdd(&deg[d], 1);
        esrc[pos] = s;
    }
}

// ---------------- 2-product bf16 MFMA GEMM + fused alpha + bf16 output ----------------
// C[M,256] = A[M,K] @ W[K,256];  A in plain bf16, W split hi/lo (correlated error kept small).
// Writes Cb (bf16) and per-node alpha_src/alpha_dst. Wave w owns head w's 64 columns.
template <bool SPLIT_A>
__global__ __launch_bounds__(256) void gemm_mfma(const float* __restrict__ Af32,
                                                 const unsigned short* __restrict__ Abg,
                                                 const unsigned short* __restrict__ Wth,
                                                 const unsigned short* __restrict__ Wtl,
                                                 const float* __restrict__ a_s,
                                                 const float* __restrict__ a_d,
                                                 unsigned short* __restrict__ Cb,
                                                 float* __restrict__ asrcO,
                                                 float* __restrict__ adstO,
                                                 int M, int K) {
    __shared__ unsigned short Ab[64][40];                // 32 + 8 pad (80B stride, conflict-free)
    __shared__ unsigned short Bh[256][40], Bl[256][40];
    int t  = threadIdx.x;
    int m0 = blockIdx.x * 64;
    int w  = t >> 6, l = t & 63;
    int lr = l & 15, lk = (l >> 4) * 8;

    float asv[4], adv[4];
    #pragma unroll
    for (int nf = 0; nf < 4; ++nf) {
        asv[nf] = a_s[w * 64 + nf * 16 + lr];
        adv[nf] = a_d[w * 64 + nf * 16 + lr];
    }

    float4v acc[4][4];
    #pragma unroll
    for (int mf = 0; mf < 4; ++mf)
        #pragma unroll
        for (int nf = 0; nf < 4; ++nf)
            acc[mf][nf] = (float4v){0.f, 0.f, 0.f, 0.f};

    for (int k0 = 0; k0 < K; k0 += 32) {
        if (SPLIT_A) {
            #pragma unroll
            for (int p = 0; p < 2; ++p) {
                int idx = t + p * 256;
                int r = idx >> 3, c4 = (idx & 7) * 4;
                int gr = m0 + r;
                float4 v = make_float4(0.f, 0.f, 0.f, 0.f);
                if (gr < M) v = *(const float4*)&Af32[(size_t)gr * K + k0 + c4];
                ushort4 hi;
                hi.x = f2bf(v.x); hi.y = f2bf(v.y); hi.z = f2bf(v.z); hi.w = f2bf(v.w);
                *(ushort4*)&Ab[r][c4] = hi;
            }
        } else {
            int r = t >> 2, c8 = (t & 3) * 8;
            int gr = m0 + r;
            short8v vh = {0,0,0,0,0,0,0,0};
            if (gr < M) vh = *(const short8v*)&Abg[(size_t)gr * K + k0 + c8];
            *(short8v*)&Ab[r][c8] = vh;
        }
        #pragma unroll
        for (int p = 0; p < 4; ++p) {
            int idx = t + p * 256;
            int r = idx >> 2, c8 = (idx & 3) * 8;
            short8v vh = *(const short8v*)&Wth[(size_t)r * K + k0 + c8];
            short8v vl = *(const short8v*)&Wtl[(size_t)r * K + k0 + c8];
            *(short8v*)&Bh[r][c8] = vh;
            *(short8v*)&Bl[r][c8] = vl;
        }
        __syncthreads();

        short8v a_f[4], b_hf[4], b_lf[4];
        #pragma unroll
        for (int mf = 0; mf < 4; ++mf)
            a_f[mf] = *(short8v*)&Ab[mf * 16 + lr][lk];
        #pragma unroll
        for (int nf = 0; nf < 4; ++nf) {
            b_hf[nf] = *(short8v*)&Bh[w * 64 + nf * 16 + lr][lk];
            b_lf[nf] = *(short8v*)&Bl[w * 64 + nf * 16 + lr][lk];
        }
        #pragma unroll
        for (int mf = 0; mf < 4; ++mf)
            #pragma unroll
            for (int nf = 0; nf < 4; ++nf) {
                acc[mf][nf] = __builtin_amdgcn_mfma_f32_16x16x32_bf16(a_f[mf], b_hf[nf], acc[mf][nf], 0, 0, 0);
                acc[mf][nf] = __builtin_amdgcn_mfma_f32_16x16x32_bf16(a_f[mf], b_lf[nf], acc[mf][nf], 0, 0, 0);
            }
        __syncthreads();
    }

    // ---- fused alpha: per-row dot with a_s/a_d (head w), 16-lane reduce ----
    #pragma unroll
    for (int mf = 0; mf < 4; ++mf)
        #pragma unroll
        for (int r = 0; r < 4; ++r) {
            float ps = acc[mf][0][r] * asv[0] + acc[mf][1][r] * asv[1]
                     + acc[mf][2][r] * asv[2] + acc[mf][3][r] * asv[3];
            float pd = acc[mf][0][r] * adv[0] + acc[mf][1][r] * adv[1]
                     + acc[mf][2][r] * adv[2] + acc[mf][3][r] * adv[3];
            #pragma unroll
            for (int o = 8; o; o >>= 1) {
                ps += __shfl_xor(ps, o);
                pd += __shfl_xor(pd, o);
            }
            int gr = m0 + mf * 16 + (l >> 4) * 4 + r;
            if (lr == 0 && gr < M) {
                asrcO[gr * 4 + w] = ps;
                adstO[gr * 4 + w] = pd;
            }
        }

    // ---- bf16 C write (gather source for agg) ----
    #pragma unroll
    for (int mf = 0; mf < 4; ++mf)
        #pragma unroll
        for (int nf = 0; nf < 4; ++nf)
            #pragma unroll
            for (int r = 0; r < 4; ++r) {
                int gr = m0 + mf * 16 + (l >> 4) * 4 + r;
                if (gr < M) Cb[(size_t)gr * F1 + w * 64 + nf * 16 + lr] = f2bf(acc[mf][nf][r]);
            }
}

// ---------------- fused segment softmax + aggregation (one wave per dst node) ----------------
// Lane owns channels lane*4..lane*4+3 (head lane>>4): ONE ushort4 gather per edge.
// LAYER 1: out = bf16 relu(agg + bias); LAYER 2: f32 head-mean + bias.
template <int LAYER>
__global__ void agg_kernel(const unsigned short* __restrict__ hb,
                           const float* __restrict__ asrc,
                           const float* __restrict__ adst,
                           const int* __restrict__ off,
                           const int* __restrict__ esrc,
                           const float* __restrict__ bias,
                           float* __restrict__ outF,
                           unsigned short* __restrict__ oh) {
    __shared__ int   soff[64];            // precomputed byte offsets s*512
    __shared__ float cf[64][4];
    int d    = blockIdx.x;
    int lane = threadIdx.x;  // 64 = 1 wave
    int w    = lane >> 4;    // this lane's head
    int e0 = off[d], e1 = off[d + 1];
    float4 ad = *(const float4*)(adst + (size_t)d * 4);
    float den = 0.f;
    float a0 = 0.f, a1 = 0.f, a2 = 0.f, a3 = 0.f;
    const char* hbase = (const char*)hb;
    int lb = lane * 8;                    // this lane's byte offset within a row

    for (int base = e0; base < e1; base += 64) {
        int cnt = min(64, e1 - base);
        if (lane < cnt) {
            int s = esrc[base + lane];
            soff[lane] = s * (F1 * 2);
            float4 as = *(const float4*)(asrc + (size_t)s * 4);
            cf[lane][0] = __expf(lrelu(as.x + ad.x));
            cf[lane][1] = __expf(lrelu(as.y + ad.y));
            cf[lane][2] = __expf(lrelu(as.z + ad.z));
            cf[lane][3] = __expf(lrelu(as.w + ad.w));
        }
        __syncthreads();
        int i = 0;
        for (; i + 4 <= cnt; i += 4) {
            int o0 = soff[i], o1 = soff[i + 1], o2 = soff[i + 2], o3 = soff[i + 3];
            ushort4 h0 = *(const ushort4*)(hbase + o0 + lb);
            ushort4 h1 = *(const ushort4*)(hbase + o1 + lb);
            ushort4 h2 = *(const ushort4*)(hbase + o2 + lb);
            ushort4 h3 = *(const ushort4*)(hbase + o3 + lb);
            float c0 = cf[i][w], c1 = cf[i + 1][w], c2 = cf[i + 2][w], c3 = cf[i + 3][w];
            den += (c0 + c1) + (c2 + c3);
            a0 += c0 * bf2f(h0.x) + c1 * bf2f(h1.x) + c2 * bf2f(h2.x) + c3 * bf2f(h3.x);
            a1 += c0 * bf2f(h0.y) + c1 * bf2f(h1.y) + c2 * bf2f(h2.y) + c3 * bf2f(h3.y);
            a2 += c0 * bf2f(h0.z) + c1 * bf2f(h1.z) + c2 * bf2f(h2.z) + c3 * bf2f(h3.z);
            a3 += c0 * bf2f(h0.w) + c1 * bf2f(h1.w) + c2 * bf2f(h2.w) + c3 * bf2f(h3.w);
        }
        for (; i < cnt; ++i) {
            int o = soff[i];
            float c = cf[i][w];
            ushort4 hv = *(const ushort4*)(hbase + o + lb);
            den += c;
            a0 += c * bf2f(hv.x);
            a1 += c * bf2f(hv.y);
            a2 += c * bf2f(hv.z);
            a3 += c * bf2f(hv.w);
        }
        __syncthreads();
    }

    float r = 1.f / fmaxf(den, 1e-16f);
    if (LAYER == 1) {
        ushort4 hi;
        hi.x = f2bf(fmaxf(a0 * r + bias[lane * 4 + 0], 0.f));
        hi.y = f2bf(fmaxf(a1 * r + bias[lane * 4 + 1], 0.f));
        hi.z = f2bf(fmaxf(a2 * r + bias[lane * 4 + 2], 0.f));
        hi.w = f2bf(fmaxf(a3 * r + bias[lane * 4 + 3], 0.f));
        *(ushort4*)&oh[(size_t)d * F1 + lane * 4] = hi;
    } else {
        float v0 = a0 * r, v1 = a1 * r, v2 = a2 * r, v3 = a3 * r;
        // head-mean: lanes {L, L^16, L^32, L^48} hold same hid for heads 0..3
        v0 += __shfl_xor(v0, 16); v0 += __shfl_xor(v0, 32);
        v1 += __shfl_xor(v1, 16); v1 += __shfl_xor(v1, 32);
        v2 += __shfl_xor(v2, 16); v2 += __shfl_xor(v2, 32);
        v3 += __shfl_xor(v3, 16); v3 += __shfl_xor(v3, 32);
        if (lane < 16) {
            float4 o;
            o.x = 0.25f * v0 + bias[lane * 4 + 0];
            o.y = 0.25f * v1 + bias[lane * 4 + 1];
            o.z = 0.25f * v2 + bias[lane * 4 + 2];
            o.w = 0.25f * v3 + bias[lane * 4 + 3];
            *(float4*)&outF[(size_t)d * HID + lane * 4] = o;
        }
    }
}

// ---------------- fused global mean pool + graph MLP: one block per graph ----------------
__device__ __forceinline__ int lowerb(const int* __restrict__ a, int n, int v) {
    int lo = 0, hi = n;
    while (lo < hi) { int m = (lo + hi) >> 1; if (a[m] < v) lo = m + 1; else hi = m; }
    return lo;
}

__global__ void poolmlp_kernel(const float* __restrict__ h2,
                               const int* __restrict__ batch,
                               const float* __restrict__ Wm1, const float* __restrict__ bm1,
                               const float* __restrict__ Wm2, const float* __restrict__ bm2,
                               float* __restrict__ out) {
    __shared__ float sh[4][HID];
    int b = blockIdx.x;
    int t = threadIdx.x, w = t >> 6, c = t & 63;
    int lo = lowerb(batch, N_NODES, b);
    int hi = lowerb(batch, N_NODES, b + 1);
    float s = 0.f;
    for (int n = lo + w; n < hi; n += 4) s += h2[(size_t)n * HID + c];
    sh[w][c] = s;
    __syncthreads();
    if (w == 0) {
        float inv = 1.f / fmaxf((float)(hi - lo), 1.f);
        float P = (sh[0][c] + sh[1][c] + sh[2][c] + sh[3][c]) * inv;
        sh[0][c] = P;
        float s1 = bm1[c];
        #pragma unroll
        for (int k = 0; k < HID; ++k) s1 += sh[0][k] * Wm1[k * HID + c];
        float r = fmaxf(s1, 0.f) * Wm2[c];
        #pragma unroll
        for (int o = 32; o; o >>= 1) r += __shfl_xor(r, o);
        if (c == 0) out[b] = r + bm2[0];
    }
}

extern "C" void kernel_launch(void* const* d_in, const int* in_sizes, int n_in,
                              void* d_out, int out_size, void* d_ws, size_t ws_size,
                              hipStream_t stream) {
    const float* x   = (const float*)d_in[0];
    const int*   ei  = (const int*)d_in[1];
    const int*   bat = (const int*)d_in[2];
    const float* W1  = (const float*)d_in[3];
    const float* as1 = (const float*)d_in[4];
    const float* ad1 = (const float*)d_in[5];
    const float* b1  = (const float*)d_in[6];
    const float* W2  = (const float*)d_in[7];
    const float* as2 = (const float*)d_in[8];
    const float* ad2 = (const float*)d_in[9];
    const float* b2  = (const float*)d_in[10];
    const float* Wm1 = (const float*)d_in[11];
    const float* bm1 = (const float*)d_in[12];
    const float* Wm2 = (const float*)d_in[13];
    const float* bm2 = (const float*)d_in[14];
    float* out = (float*)d_out;

    char* ws = (char*)d_ws;
    size_t cursor = 0;
    auto alloc = [&](size_t bytes) {
        void* p = ws + cursor;
        cursor += (bytes + 511) & ~(size_t)511;
        return p;
    };
    int*   deg    = (int*)alloc((size_t)N_NODES * 4);
    int*   off    = (int*)alloc((size_t)(N_NODES + 1) * 4);
    int*   part   = (int*)alloc((size_t)SCAN_NBLK * 4);
    int*   esrc   = (int*)alloc((size_t)ETOT * 4);
    unsigned short* bufHb = (unsigned short*)alloc((size_t)N_NODES * F1 * 2);  // gemm bf16 out
    // union region: oh (agg1 bf16 out) / bufO (agg2 f32 out) alias
    char*  U      = (char*)alloc((size_t)N_NODES * F1 * 4);
    unsigned short* oh = (unsigned short*)U;
    float* bufO   = (float*)U;
    float* asrc   = (float*)alloc((size_t)N_NODES * HEADS * 4);
    float* adst   = (float*)alloc((size_t)N_NODES * HEADS * 4);
    unsigned short* W1th = (unsigned short*)alloc((size_t)256 * IN_C * 2);
    unsigned short* W1tl = (unsigned short*)alloc((size_t)256 * IN_C * 2);
    unsigned short* W2th = (unsigned short*)alloc((size_t)256 * F1 * 2);
    unsigned short* W2tl = (unsigned short*)alloc((size_t)256 * F1 * 2);

    // fused preprocessing (cooperative: zero+convw | deg | scan | scatter)
    {
        void* args[] = { (void*)&ei, (void*)&W1, (void*)&W2,
                         (void*)&deg, (void*)&off, (void*)&part, (void*)&esrc,
                         (void*)&W1th, (void*)&W1tl, (void*)&W2th, (void*)&W2tl };
        hipLaunchCooperativeKernel((void*)prep_kernel, dim3(PREP_BLOCKS), dim3(256),
                                   args, 0, stream);
    }

    const int GB = (N_NODES + 63) / 64;
    // layer 1 (gemm writes bf16 h + alpha_src/dst; agg gathers bf16, emits bf16)
    gemm_mfma<true><<<GB, 256, 0, stream>>>(x, nullptr, W1th, W1tl,
                                            as1, ad1, bufHb, asrc, adst, N_NODES, IN_C);
    agg_kernel<1><<<N_NODES, 64, 0, stream>>>(bufHb, asrc, adst, off, esrc, b1,
                                              nullptr, oh);

    // layer 2
    gemm_mfma<false><<<GB, 256, 0, stream>>>(nullptr, oh, W2th, W2tl,
                                             as2, ad2, bufHb, asrc, adst, N_NODES, F1);
    agg_kernel<2><<<N_NODES, 64, 0, stream>>>(bufHb, asrc, adst, off, esrc, b2,
                                              bufO, nullptr);

    // fused pool + MLP (batch sorted -> binary-search ranges; 64 blocks)
    poolmlp_kernel<<<NB, 256, 0, stream>>>(bufO, bat, Wm1, bm1, Wm2, bm2, out);
}

// Round 11
// 376.957 us; speedup vs baseline: 2.2713x; 2.2713x over previous
//
#include <hip/hip_runtime.h>
#include <hip/hip_bf16.h>

#define N_NODES 50000
#define N_EDGES 800000
#define ETOT    (N_EDGES + N_NODES)
#define NB      64
#define IN_C    128
#define HID     64
#define HEADS   4
#define F1      (HEADS * HID)   /* 256 */
#define NEG     0.2f
#define SCAN_NBLK ((N_NODES + 255) / 256)   /* 196 */

typedef __attribute__((ext_vector_type(8))) short  short8v;
typedef __attribute__((ext_vector_type(4))) float  float4v;

__device__ __forceinline__ float lrelu(float x) { return x >= 0.f ? x : NEG * x; }

// round-to-nearest-even f32 -> bf16 bits
__device__ __forceinline__ unsigned short f2bf(float f) {
    unsigned u = __float_as_uint(f);
    u += 0x7FFFu + ((u >> 16) & 1u);
    return (unsigned short)(u >> 16);
}
__device__ __forceinline__ float bf2f(unsigned short h) {
    return __uint_as_float(((unsigned)h) << 16);
}

// ---------------- CSR build: degree count + (fused) W conversion ----------------
__global__ void deg_kernel(const int* __restrict__ ei, int* __restrict__ deg,
                           const float* __restrict__ W1,
                           unsigned short* __restrict__ W1h, unsigned short* __restrict__ W1l,
                           const float* __restrict__ W2,
                           unsigned short* __restrict__ W2h, unsigned short* __restrict__ W2l) {
    int e = blockIdx.x * 256 + threadIdx.x;
    // fused W1/W2 split-transpose (independent small work rides along)
    const int N1 = IN_C * 256;
    if (e < N1) {
        int k = e >> 8, n = e & 255;
        float v = W1[e];
        unsigned short h = f2bf(v);
        W1h[n * IN_C + k] = h;
        W1l[n * IN_C + k] = f2bf(v - bf2f(h));
    } else if (e < N1 + F1 * 256) {
        int j = e - N1;
        int k = j >> 8, n = j & 255;
        float v = W2[j];
        unsigned short h = f2bf(v);
        W2h[n * F1 + k] = h;
        W2l[n * F1 + k] = f2bf(v - bf2f(h));
    }
    if (e >= ETOT) return;
    int d = (e < N_EDGES) ? ei[N_EDGES + e] : (e - N_EDGES);
    atomicAdd(&deg[d], 1);
}

// 3-phase grid-wide exclusive scan of deg[N_NODES] -> off[N_NODES+1]
__global__ void scan1_kernel(const int* __restrict__ deg, int* __restrict__ part) {
    __shared__ int sh[256];
    int t = threadIdx.x;
    int i = blockIdx.x * 256 + t;
    sh[t] = (i < N_NODES) ? deg[i] : 0;
    __syncthreads();
    #pragma unroll
    for (int o = 128; o; o >>= 1) {
        if (t < o) sh[t] += sh[t + o];
        __syncthreads();
    }
    if (t == 0) part[blockIdx.x] = sh[0];
}

__global__ void scan2_kernel(int* __restrict__ part, int* __restrict__ off) {
    __shared__ int sh[256];
    int t = threadIdx.x;
    int v = (t < SCAN_NBLK) ? part[t] : 0;
    sh[t] = v;
    __syncthreads();
    #pragma unroll
    for (int o = 1; o < 256; o <<= 1) {
        int u = (t >= o) ? sh[t - o] : 0;
        __syncthreads();
        sh[t] += u;
        __syncthreads();
    }
    if (t < SCAN_NBLK) part[t] = sh[t] - v;       // exclusive block base
    if (t == 255) off[N_NODES] = sh[255];
}

__global__ void scan3_kernel(int* __restrict__ deg, const int* __restrict__ part,
                             int* __restrict__ off) {
    __shared__ int sh[256];
    int t = threadIdx.x;
    int i = blockIdx.x * 256 + t;
    int v = (i < N_NODES) ? deg[i] : 0;
    sh[t] = v;
    __syncthreads();
    #pragma unroll
    for (int o = 1; o < 256; o <<= 1) {
        int u = (t >= o) ? sh[t - o] : 0;
        __syncthreads();
        sh[t] += u;
        __syncthreads();
    }
    if (i < N_NODES) {
        off[i] = part[blockIdx.x] + sh[t] - v;
        deg[i] = 0;                                // reuse as cursor
    }
}

__global__ void scatter_kernel(const int* __restrict__ ei, const int* __restrict__ off,
                               int* __restrict__ cursor, int* __restrict__ esrc) {
    int e = blockIdx.x * 256 + threadIdx.x;
    if (e >= ETOT) return;
    int s, d;
    if (e < N_EDGES) { s = ei[e]; d = ei[N_EDGES + e]; }
    else             { s = d = e - N_EDGES; }
    int pos = off[d] + atomicAdd(&cursor[d], 1);
    esrc[pos] = s;
}

// ---------------- 2-product bf16 MFMA GEMM (BM=128) + fused alpha + bf16 output -------
// C[M,256] = A[M,K] @ W[K,256]; A plain bf16, W split hi/lo.
// 128 rows/block: halves B-staging traffic & barriers per output row vs BM=64.
template <bool SPLIT_A>
__global__ __launch_bounds__(256) void gemm_mfma(const float* __restrict__ Af32,
                                                 const unsigned short* __restrict__ Abg,
                                                 const unsigned short* __restrict__ Wth,
                                                 const unsigned short* __restrict__ Wtl,
                                                 const float* __restrict__ a_s,
                                                 const float* __restrict__ a_d,
                                                 unsigned short* __restrict__ Cb,
                                                 float* __restrict__ asrcO,
                                                 float* __restrict__ adstO,
                                                 int M, int K) {
    __shared__ unsigned short Ab[128][40];               // 32 + 8 pad (80B stride)
    __shared__ unsigned short Bh[256][40], Bl[256][40];
    int t  = threadIdx.x;
    int m0 = blockIdx.x * 128;
    int w  = t >> 6, l = t & 63;
    int lr = l & 15, lk = (l >> 4) * 8;

    float asv[4], adv[4];
    #pragma unroll
    for (int nf = 0; nf < 4; ++nf) {
        asv[nf] = a_s[w * 64 + nf * 16 + lr];
        adv[nf] = a_d[w * 64 + nf * 16 + lr];
    }

    float4v acc[8][4];
    #pragma unroll
    for (int mf = 0; mf < 8; ++mf)
        #pragma unroll
        for (int nf = 0; nf < 4; ++nf)
            acc[mf][nf] = (float4v){0.f, 0.f, 0.f, 0.f};

    for (int k0 = 0; k0 < K; k0 += 32) {
        if (SPLIT_A) {
            // 128 rows x 32 cols f32 = 1024 float4 chunks
            #pragma unroll
            for (int p = 0; p < 4; ++p) {
                int idx = t + p * 256;
                int r = idx >> 3, c4 = (idx & 7) * 4;
                int gr = m0 + r;
                float4 v = make_float4(0.f, 0.f, 0.f, 0.f);
                if (gr < M) v = *(const float4*)&Af32[(size_t)gr * K + k0 + c4];
                ushort4 hi;
                hi.x = f2bf(v.x); hi.y = f2bf(v.y); hi.z = f2bf(v.z); hi.w = f2bf(v.w);
                *(ushort4*)&Ab[r][c4] = hi;
            }
        } else {
            // 128 rows x 32 bf16 = 512 short8v chunks
            #pragma unroll
            for (int p = 0; p < 2; ++p) {
                int idx = t + p * 256;
                int r = idx >> 2, c8 = (idx & 3) * 8;
                int gr = m0 + r;
                short8v vh = {0,0,0,0,0,0,0,0};
                if (gr < M) vh = *(const short8v*)&Abg[(size_t)gr * K + k0 + c8];
                *(short8v*)&Ab[r][c8] = vh;
            }
        }
        #pragma unroll
        for (int p = 0; p < 4; ++p) {
            int idx = t + p * 256;
            int r = idx >> 2, c8 = (idx & 3) * 8;
            short8v vh = *(const short8v*)&Wth[(size_t)r * K + k0 + c8];
            short8v vl = *(const short8v*)&Wtl[(size_t)r * K + k0 + c8];
            *(short8v*)&Bh[r][c8] = vh;
            *(short8v*)&Bl[r][c8] = vl;
        }
        __syncthreads();

        short8v b_hf[4], b_lf[4];
        #pragma unroll
        for (int nf = 0; nf < 4; ++nf) {
            b_hf[nf] = *(short8v*)&Bh[w * 64 + nf * 16 + lr][lk];
            b_lf[nf] = *(short8v*)&Bl[w * 64 + nf * 16 + lr][lk];
        }
        #pragma unroll
        for (int mf = 0; mf < 8; ++mf) {
            short8v a_f = *(short8v*)&Ab[mf * 16 + lr][lk];
            #pragma unroll
            for (int nf = 0; nf < 4; ++nf) {
                acc[mf][nf] = __builtin_amdgcn_mfma_f32_16x16x32_bf16(a_f, b_hf[nf], acc[mf][nf], 0, 0, 0);
                acc[mf][nf] = __builtin_amdgcn_mfma_f32_16x16x32_bf16(a_f, b_lf[nf], acc[mf][nf], 0, 0, 0);
            }
        }
        __syncthreads();
    }

    // ---- fused alpha: per-row dot with a_s/a_d (head w), 16-lane reduce ----
    #pragma unroll
    for (int mf = 0; mf < 8; ++mf)
        #pragma unroll
        for (int r = 0; r < 4; ++r) {
            float ps = acc[mf][0][r] * asv[0] + acc[mf][1][r] * asv[1]
                     + acc[mf][2][r] * asv[2] + acc[mf][3][r] * asv[3];
            float pd = acc[mf][0][r] * adv[0] + acc[mf][1][r] * adv[1]
                     + acc[mf][2][r] * adv[2] + acc[mf][3][r] * adv[3];
            #pragma unroll
            for (int o = 8; o; o >>= 1) {
                ps += __shfl_xor(ps, o);
                pd += __shfl_xor(pd, o);
            }
            int gr = m0 + mf * 16 + (l >> 4) * 4 + r;
            if (lr == 0 && gr < M) {
                asrcO[gr * 4 + w] = ps;
                adstO[gr * 4 + w] = pd;
            }
        }

    // ---- bf16 C write (gather source for agg) ----
    #pragma unroll
    for (int mf = 0; mf < 8; ++mf)
        #pragma unroll
        for (int nf = 0; nf < 4; ++nf)
            #pragma unroll
            for (int r = 0; r < 4; ++r) {
                int gr = m0 + mf * 16 + (l >> 4) * 4 + r;
                if (gr < M) Cb[(size_t)gr * F1 + w * 64 + nf * 16 + lr] = f2bf(acc[mf][nf][r]);
            }
}

// ---------------- fused segment softmax + aggregation (one wave per dst node) ----------------
// Lane owns channels lane*4..lane*4+3 (head lane>>4): ONE ushort4 gather per edge.
// LAYER 1: out = bf16 relu(agg + bias); LAYER 2: f32 head-mean + bias.
template <int LAYER>
__global__ void agg_kernel(const unsigned short* __restrict__ hb,
                           const float* __restrict__ asrc,
                           const float* __restrict__ adst,
                           const int* __restrict__ off,
                           const int* __restrict__ esrc,
                           const float* __restrict__ bias,
                           float* __restrict__ outF,
                           unsigned short* __restrict__ oh) {
    __shared__ int   soff[64];            // precomputed byte offsets s*512
    __shared__ float cf[64][4];
    int d    = blockIdx.x;
    int lane = threadIdx.x;  // 64 = 1 wave
    int w    = lane >> 4;    // this lane's head
    int e0 = off[d], e1 = off[d + 1];
    float4 ad = *(const float4*)(adst + (size_t)d * 4);
    float den = 0.f;
    float a0 = 0.f, a1 = 0.f, a2 = 0.f, a3 = 0.f;
    const char* hbase = (const char*)hb;
    int lb = lane * 8;                    // this lane's byte offset within a row

    for (int base = e0; base < e1; base += 64) {
        int cnt = min(64, e1 - base);
        if (lane < cnt) {
            int s = esrc[base + lane];
            soff[lane] = s * (F1 * 2);
            float4 as = *(const float4*)(asrc + (size_t)s * 4);
            cf[lane][0] = __expf(lrelu(as.x + ad.x));
            cf[lane][1] = __expf(lrelu(as.y + ad.y));
            cf[lane][2] = __expf(lrelu(as.z + ad.z));
            cf[lane][3] = __expf(lrelu(as.w + ad.w));
        }
        __syncthreads();
        int i = 0;
        for (; i + 4 <= cnt; i += 4) {
            int o0 = soff[i], o1 = soff[i + 1], o2 = soff[i + 2], o3 = soff[i + 3];
            ushort4 h0 = *(const ushort4*)(hbase + o0 + lb);
            ushort4 h1 = *(const ushort4*)(hbase + o1 + lb);
            ushort4 h2 = *(const ushort4*)(hbase + o2 + lb);
            ushort4 h3 = *(const ushort4*)(hbase + o3 + lb);
            float c0 = cf[i][w], c1 = cf[i + 1][w], c2 = cf[i + 2][w], c3 = cf[i + 3][w];
            den += (c0 + c1) + (c2 + c3);
            a0 += c0 * bf2f(h0.x) + c1 * bf2f(h1.x) + c2 * bf2f(h2.x) + c3 * bf2f(h3.x);
            a1 += c0 * bf2f(h0.y) + c1 * bf2f(h1.y) + c2 * bf2f(h2.y) + c3 * bf2f(h3.y);
            a2 += c0 * bf2f(h0.z) + c1 * bf2f(h1.z) + c2 * bf2f(h2.z) + c3 * bf2f(h3.z);
            a3 += c0 * bf2f(h0.w) + c1 * bf2f(h1.w) + c2 * bf2f(h2.w) + c3 * bf2f(h3.w);
        }
        for (; i < cnt; ++i) {
            int o = soff[i];
            float c = cf[i][w];
            ushort4 hv = *(const ushort4*)(hbase + o + lb);
            den += c;
            a0 += c * bf2f(hv.x);
            a1 += c * bf2f(hv.y);
            a2 += c * bf2f(hv.z);
            a3 += c * bf2f(hv.w);
        }
        __syncthreads();
    }

    float r = 1.f / fmaxf(den, 1e-16f);
    if (LAYER == 1) {
        ushort4 hi;
        hi.x = f2bf(fmaxf(a0 * r + bias[lane * 4 + 0], 0.f));
        hi.y = f2bf(fmaxf(a1 * r + bias[lane * 4 + 1], 0.f));
        hi.z = f2bf(fmaxf(a2 * r + bias[lane * 4 + 2], 0.f));
        hi.w = f2bf(fmaxf(a3 * r + bias[lane * 4 + 3], 0.f));
        *(ushort4*)&oh[(size_t)d * F1 + lane * 4] = hi;
    } else {
        float v0 = a0 * r, v1 = a1 * r, v2 = a2 * r, v3 = a3 * r;
        // head-mean: lanes {L, L^16, L^32, L^48} hold same hid for heads 0..3
        v0 += __shfl_xor(v0, 16); v0 += __shfl_xor(v0, 32);
        v1 += __shfl_xor(v1, 16); v1 += __shfl_xor(v1, 32);
        v2 += __shfl_xor(v2, 16); v2 += __shfl_xor(v2, 32);
        v3 += __shfl_xor(v3, 16); v3 += __shfl_xor(v3, 32);
        if (lane < 16) {
            float4 o;
            o.x = 0.25f * v0 + bias[lane * 4 + 0];
            o.y = 0.25f * v1 + bias[lane * 4 + 1];
            o.z = 0.25f * v2 + bias[lane * 4 + 2];
            o.w = 0.25f * v3 + bias[lane * 4 + 3];
            *(float4*)&outF[(size_t)d * HID + lane * 4] = o;
        }
    }
}

// ---------------- fused global mean pool + graph MLP: one block per graph ----------------
__device__ __forceinline__ int lowerb(const int* __restrict__ a, int n, int v) {
    int lo = 0, hi = n;
    while (lo < hi) { int m = (lo + hi) >> 1; if (a[m] < v) lo = m + 1; else hi = m; }
    return lo;
}

__global__ void poolmlp_kernel(const float* __restrict__ h2,
                               const int* __restrict__ batch,
                               const float* __restrict__ Wm1, const float* __restrict__ bm1,
                               const float* __restrict__ Wm2, const float* __restrict__ bm2,
                               float* __restrict__ out) {
    __shared__ float sh[4][HID];
    int b = blockIdx.x;
    int t = threadIdx.x, w = t >> 6, c = t & 63;
    int lo = lowerb(batch, N_NODES, b);
    int hi = lowerb(batch, N_NODES, b + 1);
    float s = 0.f;
    for (int n = lo + w; n < hi; n += 4) s += h2[(size_t)n * HID + c];
    sh[w][c] = s;
    __syncthreads();
    if (w == 0) {
        float inv = 1.f / fmaxf((float)(hi - lo), 1.f);
        float P = (sh[0][c] + sh[1][c] + sh[2][c] + sh[3][c]) * inv;
        sh[0][c] = P;
        float s1 = bm1[c];
        #pragma unroll
        for (int k = 0; k < HID; ++k) s1 += sh[0][k] * Wm1[k * HID + c];
        float r = fmaxf(s1, 0.f) * Wm2[c];
        #pragma unroll
        for (int o = 32; o; o >>= 1) r += __shfl_xor(r, o);
        if (c == 0) out[b] = r + bm2[0];
    }
}

extern "C" void kernel_launch(void* const* d_in, const int* in_sizes, int n_in,
                              void* d_out, int out_size, void* d_ws, size_t ws_size,
                              hipStream_t stream) {
    const float* x   = (const float*)d_in[0];
    const int*   ei  = (const int*)d_in[1];
    const int*   bat = (const int*)d_in[2];
    const float* W1  = (const float*)d_in[3];
    const float* as1 = (const float*)d_in[4];
    const float* ad1 = (const float*)d_in[5];
    const float* b1  = (const float*)d_in[6];
    const float* W2  = (const float*)d_in[7];
    const float* as2 = (const float*)d_in[8];
    const float* ad2 = (const float*)d_in[9];
    const float* b2  = (const float*)d_in[10];
    const float* Wm1 = (const float*)d_in[11];
    const float* bm1 = (const float*)d_in[12];
    const float* Wm2 = (const float*)d_in[13];
    const float* bm2 = (const float*)d_in[14];
    float* out = (float*)d_out;

    char* ws = (char*)d_ws;
    size_t cursor = 0;
    auto alloc = [&](size_t bytes) {
        void* p = ws + cursor;
        cursor += (bytes + 511) & ~(size_t)511;
        return p;
    };
    int*   deg    = (int*)alloc((size_t)N_NODES * 4);
    int*   off    = (int*)alloc((size_t)(N_NODES + 1) * 4);
    int*   part   = (int*)alloc((size_t)SCAN_NBLK * 4);
    int*   esrc   = (int*)alloc((size_t)ETOT * 4);
    unsigned short* bufHb = (unsigned short*)alloc((size_t)N_NODES * F1 * 2);  // gemm bf16 out
    // union region: oh (agg1 bf16 out) / bufO (agg2 f32 out) alias
    char*  U      = (char*)alloc((size_t)N_NODES * F1 * 4);
    unsigned short* oh = (unsigned short*)U;
    float* bufO   = (float*)U;
    float* asrc   = (float*)alloc((size_t)N_NODES * HEADS * 4);
    float* adst   = (float*)alloc((size_t)N_NODES * HEADS * 4);
    unsigned short* W1th = (unsigned short*)alloc((size_t)256 * IN_C * 2);
    unsigned short* W1tl = (unsigned short*)alloc((size_t)256 * IN_C * 2);
    unsigned short* W2th = (unsigned short*)alloc((size_t)256 * F1 * 2);
    unsigned short* W2tl = (unsigned short*)alloc((size_t)256 * F1 * 2);

    hipMemsetAsync(deg, 0, (size_t)N_NODES * 4, stream);

    deg_kernel<<<(ETOT + 255) / 256, 256, 0, stream>>>(ei, deg, W1, W1th, W1tl,
                                                       W2, W2th, W2tl);
    scan1_kernel<<<SCAN_NBLK, 256, 0, stream>>>(deg, part);
    scan2_kernel<<<1, 256, 0, stream>>>(part, off);
    scan3_kernel<<<SCAN_NBLK, 256, 0, stream>>>(deg, part, off);
    scatter_kernel<<<(ETOT + 255) / 256, 256, 0, stream>>>(ei, off, deg, esrc);

    const int GB = (N_NODES + 127) / 128;
    // layer 1 (gemm writes bf16 h + alpha_src/dst; agg gathers bf16, emits bf16)
    gemm_mfma<true><<<GB, 256, 0, stream>>>(x, nullptr, W1th, W1tl,
                                            as1, ad1, bufHb, asrc, adst, N_NODES, IN_C);
    agg_kernel<1><<<N_NODES, 64, 0, stream>>>(bufHb, asrc, adst, off, esrc, b1,
                                              nullptr, oh);

    // layer 2
    gemm_mfma<false><<<GB, 256, 0, stream>>>(nullptr, oh, W2th, W2tl,
                                             as2, ad2, bufHb, asrc, adst, N_NODES, F1);
    agg_kernel<2><<<N_NODES, 64, 0, stream>>>(bufHb, asrc, adst, off, esrc, b2,
                                              bufO, nullptr);

    // fused pool + MLP (batch sorted -> binary-search ranges; 64 blocks)
    poolmlp_kernel<<<NB, 256, 0, stream>>>(bufO, bat, Wm1, bm1, Wm2, bm2, out);
}

// Round 12
// 362.677 us; speedup vs baseline: 2.3607x; 1.0394x over previous
//
#include <hip/hip_runtime.h>
#include <hip/hip_bf16.h>

#define N_NODES 50000
#define N_EDGES 800000
#define ETOT    (N_EDGES + N_NODES)
#define NB      64
#define IN_C    128
#define HID     64
#define HEADS   4
#define F1      (HEADS * HID)   /* 256 */
#define NEG     0.2f
#define SCAN_NBLK ((N_NODES + 255) / 256)   /* 196 */

typedef __attribute__((ext_vector_type(8))) short  short8v;
typedef __attribute__((ext_vector_type(4))) float  float4v;

__device__ __forceinline__ float lrelu(float x) { return x >= 0.f ? x : NEG * x; }

// round-to-nearest-even f32 -> bf16 bits
__device__ __forceinline__ unsigned short f2bf(float f) {
    unsigned u = __float_as_uint(f);
    u += 0x7FFFu + ((u >> 16) & 1u);
    return (unsigned short)(u >> 16);
}
__device__ __forceinline__ float bf2f(unsigned short h) {
    return __uint_as_float(((unsigned)h) << 16);
}

// fragment-linear W index: lane l of fragment (kb, ng) reads bytes [l*16, l*16+16)
// idx(k,n) = (kb*16 + ng)*512 + hi*128 + lr*8 + j ; kb=k>>5, hi=(k>>3)&3, j=k&7, ng=n>>4, lr=n&15
__device__ __forceinline__ int wf_idx(int k, int n) {
    return (((k >> 5) * 16 + (n >> 4)) << 9) + (((k >> 3) & 3) << 7) + ((n & 15) << 3) + (k & 7);
}

// ---------------- CSR build: degree count + (fused) W conversion to fragment layout ----
__global__ void deg_kernel(const int* __restrict__ ei, int* __restrict__ deg,
                           const float* __restrict__ W1,
                           unsigned short* __restrict__ W1h, unsigned short* __restrict__ W1l,
                           const float* __restrict__ W2,
                           unsigned short* __restrict__ W2h, unsigned short* __restrict__ W2l) {
    int e = blockIdx.x * 256 + threadIdx.x;
    const int N1 = IN_C * 256;
    if (e < N1) {
        int k = e >> 8, n = e & 255;
        float v = W1[e];
        unsigned short h = f2bf(v);
        int idx = wf_idx(k, n);
        W1h[idx] = h;
        W1l[idx] = f2bf(v - bf2f(h));
    } else if (e < N1 + F1 * 256) {
        int j = e - N1;
        int k = j >> 8, n = j & 255;
        float v = W2[j];
        unsigned short h = f2bf(v);
        int idx = wf_idx(k, n);
        W2h[idx] = h;
        W2l[idx] = f2bf(v - bf2f(h));
    }
    if (e >= ETOT) return;
    int d = (e < N_EDGES) ? ei[N_EDGES + e] : (e - N_EDGES);
    atomicAdd(&deg[d], 1);
}

// 3-phase grid-wide exclusive scan of deg[N_NODES] -> off[N_NODES+1]
__global__ void scan1_kernel(const int* __restrict__ deg, int* __restrict__ part) {
    __shared__ int sh[256];
    int t = threadIdx.x;
    int i = blockIdx.x * 256 + t;
    sh[t] = (i < N_NODES) ? deg[i] : 0;
    __syncthreads();
    #pragma unroll
    for (int o = 128; o; o >>= 1) {
        if (t < o) sh[t] += sh[t + o];
        __syncthreads();
    }
    if (t == 0) part[blockIdx.x] = sh[0];
}

__global__ void scan2_kernel(int* __restrict__ part, int* __restrict__ off) {
    __shared__ int sh[256];
    int t = threadIdx.x;
    int v = (t < SCAN_NBLK) ? part[t] : 0;
    sh[t] = v;
    __syncthreads();
    #pragma unroll
    for (int o = 1; o < 256; o <<= 1) {
        int u = (t >= o) ? sh[t - o] : 0;
        __syncthreads();
        sh[t] += u;
        __syncthreads();
    }
    if (t < SCAN_NBLK) part[t] = sh[t] - v;       // exclusive block base
    if (t == 255) off[N_NODES] = sh[255];
}

__global__ void scan3_kernel(int* __restrict__ deg, const int* __restrict__ part,
                             int* __restrict__ off) {
    __shared__ int sh[256];
    int t = threadIdx.x;
    int i = blockIdx.x * 256 + t;
    int v = (i < N_NODES) ? deg[i] : 0;
    sh[t] = v;
    __syncthreads();
    #pragma unroll
    for (int o = 1; o < 256; o <<= 1) {
        int u = (t >= o) ? sh[t - o] : 0;
        __syncthreads();
        sh[t] += u;
        __syncthreads();
    }
    if (i < N_NODES) {
        off[i] = part[blockIdx.x] + sh[t] - v;
        deg[i] = 0;                                // reuse as cursor
    }
}

__global__ void scatter_kernel(const int* __restrict__ ei, const int* __restrict__ off,
                               int* __restrict__ cursor, int* __restrict__ esrc) {
    int e = blockIdx.x * 256 + threadIdx.x;
    if (e >= ETOT) return;
    int s, d;
    if (e < N_EDGES) { s = ei[e]; d = ei[N_EDGES + e]; }
    else             { s = d = e - N_EDGES; }
    int pos = off[d] + atomicAdd(&cursor[d], 1);
    esrc[pos] = s;
}

// ---------------- barrier-free 2-product bf16 MFMA GEMM + fused alpha ----------------
// BM=64; A tile staged to LDS ONCE (1 barrier); B fragments read coalesced from
// fragment-linear Wf in global (L2-resident) -> no in-loop barriers at all.
template <bool SPLIT_A, int K>
__global__ __launch_bounds__(256) void gemm_mfma(const float* __restrict__ Af32,
                                                 const unsigned short* __restrict__ Abg,
                                                 const unsigned short* __restrict__ Wfh,
                                                 const unsigned short* __restrict__ Wfl,
                                                 const float* __restrict__ a_s,
                                                 const float* __restrict__ a_d,
                                                 unsigned short* __restrict__ Cb,
                                                 float* __restrict__ asrcO,
                                                 float* __restrict__ adstO,
                                                 int M) {
    __shared__ unsigned short Ab[64][K + 8];   // +8 pad -> row stride ≡ 4 banks (2-way, free)
    int t  = threadIdx.x;
    int m0 = blockIdx.x * 64;
    int w  = t >> 6, l = t & 63;
    int lr = l & 15, lk = (l >> 4) * 8;

    float asv[4], adv[4];
    #pragma unroll
    for (int nf = 0; nf < 4; ++nf) {
        asv[nf] = a_s[w * 64 + nf * 16 + lr];
        adv[nf] = a_d[w * 64 + nf * 16 + lr];
    }

    // ---- stage ENTIRE A tile (64 x K bf16), one barrier ----
    {
        int r = t >> 2, q = t & 3, gr = m0 + r;
        if (SPLIT_A) {
            #pragma unroll
            for (int c = 0; c < K / 4; c += 4) {
                int col = q * (K / 4) + c;
                float4 v = make_float4(0.f, 0.f, 0.f, 0.f);
                if (gr < M) v = *(const float4*)&Af32[(size_t)gr * K + col];
                ushort4 hi;
                hi.x = f2bf(v.x); hi.y = f2bf(v.y); hi.z = f2bf(v.z); hi.w = f2bf(v.w);
                *(ushort4*)&Ab[r][col] = hi;
            }
        } else {
            #pragma unroll
            for (int c = 0; c < K / 4; c += 8) {
                int col = q * (K / 4) + c;
                short8v vh = {0,0,0,0,0,0,0,0};
                if (gr < M) vh = *(const short8v*)&Abg[(size_t)gr * K + col];
                *(short8v*)&Ab[r][col] = vh;
            }
        }
    }
    __syncthreads();

    float4v acc[4][4];
    #pragma unroll
    for (int mf = 0; mf < 4; ++mf)
        #pragma unroll
        for (int nf = 0; nf < 4; ++nf)
            acc[mf][nf] = (float4v){0.f, 0.f, 0.f, 0.f};

    constexpr int KB = K / 32;
    #pragma unroll 2
    for (int kb = 0; kb < KB; ++kb) {
        short8v b_hf[4], b_lf[4];
        #pragma unroll
        for (int nf = 0; nf < 4; ++nf) {
            size_t bidx = (size_t)((kb * 16 + w * 4 + nf) * 512 + l * 8);
            b_hf[nf] = *(const short8v*)&Wfh[bidx];
            b_lf[nf] = *(const short8v*)&Wfl[bidx];
        }
        #pragma unroll
        for (int mf = 0; mf < 4; ++mf) {
            short8v a_f = *(short8v*)&Ab[mf * 16 + lr][kb * 32 + lk];
            #pragma unroll
            for (int nf = 0; nf < 4; ++nf) {
                acc[mf][nf] = __builtin_amdgcn_mfma_f32_16x16x32_bf16(a_f, b_hf[nf], acc[mf][nf], 0, 0, 0);
                acc[mf][nf] = __builtin_amdgcn_mfma_f32_16x16x32_bf16(a_f, b_lf[nf], acc[mf][nf], 0, 0, 0);
            }
        }
    }

    // ---- fused alpha: per-row dot with a_s/a_d (head w), 16-lane reduce ----
    #pragma unroll
    for (int mf = 0; mf < 4; ++mf)
        #pragma unroll
        for (int r = 0; r < 4; ++r) {
            float ps = acc[mf][0][r] * asv[0] + acc[mf][1][r] * asv[1]
                     + acc[mf][2][r] * asv[2] + acc[mf][3][r] * asv[3];
            float pd = acc[mf][0][r] * adv[0] + acc[mf][1][r] * adv[1]
                     + acc[mf][2][r] * adv[2] + acc[mf][3][r] * adv[3];
            #pragma unroll
            for (int o = 8; o; o >>= 1) {
                ps += __shfl_xor(ps, o);
                pd += __shfl_xor(pd, o);
            }
            int gr = m0 + mf * 16 + (l >> 4) * 4 + r;
            if (lr == 0 && gr < M) {
                asrcO[gr * 4 + w] = ps;
                adstO[gr * 4 + w] = pd;
            }
        }

    // ---- bf16 C write (gather source for agg) ----
    #pragma unroll
    for (int mf = 0; mf < 4; ++mf)
        #pragma unroll
        for (int nf = 0; nf < 4; ++nf)
            #pragma unroll
            for (int r = 0; r < 4; ++r) {
                int gr = m0 + mf * 16 + (l >> 4) * 4 + r;
                if (gr < M) Cb[(size_t)gr * F1 + w * 64 + nf * 16 + lr] = f2bf(acc[mf][nf][r]);
            }
}

// ---------------- fused segment softmax + aggregation (one wave per dst node) ----------------
// Lane owns channels lane*4..lane*4+3 (head lane>>4): ONE ushort4 gather per edge.
// LAYER 1: out = bf16 relu(agg + bias); LAYER 2: f32 head-mean + bias.
template <int LAYER>
__global__ void agg_kernel(const unsigned short* __restrict__ hb,
                           const float* __restrict__ asrc,
                           const float* __restrict__ adst,
                           const int* __restrict__ off,
                           const int* __restrict__ esrc,
                           const float* __restrict__ bias,
                           float* __restrict__ outF,
                           unsigned short* __restrict__ oh) {
    __shared__ int   soff[64];            // precomputed byte offsets s*512
    __shared__ float cf[64][4];
    int d    = blockIdx.x;
    int lane = threadIdx.x;  // 64 = 1 wave
    int w    = lane >> 4;    // this lane's head
    int e0 = off[d], e1 = off[d + 1];
    float4 ad = *(const float4*)(adst + (size_t)d * 4);
    float den = 0.f;
    float a0 = 0.f, a1 = 0.f, a2 = 0.f, a3 = 0.f;
    const char* hbase = (const char*)hb;
    int lb = lane * 8;                    // this lane's byte offset within a row

    for (int base = e0; base < e1; base += 64) {
        int cnt = min(64, e1 - base);
        if (lane < cnt) {
            int s = esrc[base + lane];
            soff[lane] = s * (F1 * 2);
            float4 as = *(const float4*)(asrc + (size_t)s * 4);
            cf[lane][0] = __expf(lrelu(as.x + ad.x));
            cf[lane][1] = __expf(lrelu(as.y + ad.y));
            cf[lane][2] = __expf(lrelu(as.z + ad.z));
            cf[lane][3] = __expf(lrelu(as.w + ad.w));
        }
        __syncthreads();
        int i = 0;
        for (; i + 4 <= cnt; i += 4) {
            int o0 = soff[i], o1 = soff[i + 1], o2 = soff[i + 2], o3 = soff[i + 3];
            ushort4 h0 = *(const ushort4*)(hbase + o0 + lb);
            ushort4 h1 = *(const ushort4*)(hbase + o1 + lb);
            ushort4 h2 = *(const ushort4*)(hbase + o2 + lb);
            ushort4 h3 = *(const ushort4*)(hbase + o3 + lb);
            float c0 = cf[i][w], c1 = cf[i + 1][w], c2 = cf[i + 2][w], c3 = cf[i + 3][w];
            den += (c0 + c1) + (c2 + c3);
            a0 += c0 * bf2f(h0.x) + c1 * bf2f(h1.x) + c2 * bf2f(h2.x) + c3 * bf2f(h3.x);
            a1 += c0 * bf2f(h0.y) + c1 * bf2f(h1.y) + c2 * bf2f(h2.y) + c3 * bf2f(h3.y);
            a2 += c0 * bf2f(h0.z) + c1 * bf2f(h1.z) + c2 * bf2f(h2.z) + c3 * bf2f(h3.z);
            a3 += c0 * bf2f(h0.w) + c1 * bf2f(h1.w) + c2 * bf2f(h2.w) + c3 * bf2f(h3.w);
        }
        for (; i < cnt; ++i) {
            int o = soff[i];
            float c = cf[i][w];
            ushort4 hv = *(const ushort4*)(hbase + o + lb);
            den += c;
            a0 += c * bf2f(hv.x);
            a1 += c * bf2f(hv.y);
            a2 += c * bf2f(hv.z);
            a3 += c * bf2f(hv.w);
        }
        __syncthreads();
    }

    float r = 1.f / fmaxf(den, 1e-16f);
    if (LAYER == 1) {
        ushort4 hi;
        hi.x = f2bf(fmaxf(a0 * r + bias[lane * 4 + 0], 0.f));
        hi.y = f2bf(fmaxf(a1 * r + bias[lane * 4 + 1], 0.f));
        hi.z = f2bf(fmaxf(a2 * r + bias[lane * 4 + 2], 0.f));
        hi.w = f2bf(fmaxf(a3 * r + bias[lane * 4 + 3], 0.f));
        *(ushort4*)&oh[(size_t)d * F1 + lane * 4] = hi;
    } else {
        float v0 = a0 * r, v1 = a1 * r, v2 = a2 * r, v3 = a3 * r;
        // head-mean: lanes {L, L^16, L^32, L^48} hold same hid for heads 0..3
        v0 += __shfl_xor(v0, 16); v0 += __shfl_xor(v0, 32);
        v1 += __shfl_xor(v1, 16); v1 += __shfl_xor(v1, 32);
        v2 += __shfl_xor(v2, 16); v2 += __shfl_xor(v2, 32);
        v3 += __shfl_xor(v3, 16); v3 += __shfl_xor(v3, 32);
        if (lane < 16) {
            float4 o;
            o.x = 0.25f * v0 + bias[lane * 4 + 0];
            o.y = 0.25f * v1 + bias[lane * 4 + 1];
            o.z = 0.25f * v2 + bias[lane * 4 + 2];
            o.w = 0.25f * v3 + bias[lane * 4 + 3];
            *(float4*)&outF[(size_t)d * HID + lane * 4] = o;
        }
    }
}

// ---------------- fused global mean pool + graph MLP: one block per graph ----------------
__device__ __forceinline__ int lowerb(const int* __restrict__ a, int n, int v) {
    int lo = 0, hi = n;
    while (lo < hi) { int m = (lo + hi) >> 1; if (a[m] < v) lo = m + 1; else hi = m; }
    return lo;
}

__global__ void poolmlp_kernel(const float* __restrict__ h2,
                               const int* __restrict__ batch,
                               const float* __restrict__ Wm1, const float* __restrict__ bm1,
                               const float* __restrict__ Wm2, const float* __restrict__ bm2,
                               float* __restrict__ out) {
    __shared__ float sh[4][HID];
    int b = blockIdx.x;
    int t = threadIdx.x, w = t >> 6, c = t & 63;
    int lo = lowerb(batch, N_NODES, b);
    int hi = lowerb(batch, N_NODES, b + 1);
    float s = 0.f;
    for (int n = lo + w; n < hi; n += 4) s += h2[(size_t)n * HID + c];
    sh[w][c] = s;
    __syncthreads();
    if (w == 0) {
        float inv = 1.f / fmaxf((float)(hi - lo), 1.f);
        float P = (sh[0][c] + sh[1][c] + sh[2][c] + sh[3][c]) * inv;
        sh[0][c] = P;
        float s1 = bm1[c];
        #pragma unroll
        for (int k = 0; k < HID; ++k) s1 += sh[0][k] * Wm1[k * HID + c];
        float r = fmaxf(s1, 0.f) * Wm2[c];
        #pragma unroll
        for (int o = 32; o; o >>= 1) r += __shfl_xor(r, o);
        if (c == 0) out[b] = r + bm2[0];
    }
}

extern "C" void kernel_launch(void* const* d_in, const int* in_sizes, int n_in,
                              void* d_out, int out_size, void* d_ws, size_t ws_size,
                              hipStream_t stream) {
    const float* x   = (const float*)d_in[0];
    const int*   ei  = (const int*)d_in[1];
    const int*   bat = (const int*)d_in[2];
    const float* W1  = (const float*)d_in[3];
    const float* as1 = (const float*)d_in[4];
    const float* ad1 = (const float*)d_in[5];
    const float* b1  = (const float*)d_in[6];
    const float* W2  = (const float*)d_in[7];
    const float* as2 = (const float*)d_in[8];
    const float* ad2 = (const float*)d_in[9];
    const float* b2  = (const float*)d_in[10];
    const float* Wm1 = (const float*)d_in[11];
    const float* bm1 = (const float*)d_in[12];
    const float* Wm2 = (const float*)d_in[13];
    const float* bm2 = (const float*)d_in[14];
    float* out = (float*)d_out;

    char* ws = (char*)d_ws;
    size_t cursor = 0;
    auto alloc = [&](size_t bytes) {
        void* p = ws + cursor;
        cursor += (bytes + 511) & ~(size_t)511;
        return p;
    };
    int*   deg    = (int*)alloc((size_t)N_NODES * 4);
    int*   off    = (int*)alloc((size_t)(N_NODES + 1) * 4);
    int*   part   = (int*)alloc((size_t)SCAN_NBLK * 4);
    int*   esrc   = (int*)alloc((size_t)ETOT * 4);
    unsigned short* bufHb = (unsigned short*)alloc((size_t)N_NODES * F1 * 2);  // gemm bf16 out
    // union region: oh (agg1 bf16 out) / bufO (agg2 f32 out) alias
    char*  U      = (char*)alloc((size_t)N_NODES * F1 * 4);
    unsigned short* oh = (unsigned short*)U;
    float* bufO   = (float*)U;
    float* asrc   = (float*)alloc((size_t)N_NODES * HEADS * 4);
    float* adst   = (float*)alloc((size_t)N_NODES * HEADS * 4);
    unsigned short* W1th = (unsigned short*)alloc((size_t)256 * IN_C * 2);
    unsigned short* W1tl = (unsigned short*)alloc((size_t)256 * IN_C * 2);
    unsigned short* W2th = (unsigned short*)alloc((size_t)256 * F1 * 2);
    unsigned short* W2tl = (unsigned short*)alloc((size_t)256 * F1 * 2);

    hipMemsetAsync(deg, 0, (size_t)N_NODES * 4, stream);

    deg_kernel<<<(ETOT + 255) / 256, 256, 0, stream>>>(ei, deg, W1, W1th, W1tl,
                                                       W2, W2th, W2tl);
    scan1_kernel<<<SCAN_NBLK, 256, 0, stream>>>(deg, part);
    scan2_kernel<<<1, 256, 0, stream>>>(part, off);
    scan3_kernel<<<SCAN_NBLK, 256, 0, stream>>>(deg, part, off);
    scatter_kernel<<<(ETOT + 255) / 256, 256, 0, stream>>>(ei, off, deg, esrc);

    const int GB = (N_NODES + 63) / 64;
    // layer 1 (gemm writes bf16 h + alpha_src/dst; agg gathers bf16, emits bf16)
    gemm_mfma<true, IN_C><<<GB, 256, 0, stream>>>(x, nullptr, W1th, W1tl,
                                                  as1, ad1, bufHb, asrc, adst, N_NODES);
    agg_kernel<1><<<N_NODES, 64, 0, stream>>>(bufHb, asrc, adst, off, esrc, b1,
                                              nullptr, oh);

    // layer 2
    gemm_mfma<false, F1><<<GB, 256, 0, stream>>>(nullptr, oh, W2th, W2tl,
                                                 as2, ad2, bufHb, asrc, adst, N_NODES);
    agg_kernel<2><<<N_NODES, 64, 0, stream>>>(bufHb, asrc, adst, off, esrc, b2,
                                              bufO, nullptr);

    // fused pool + MLP (batch sorted -> binary-search ranges; 64 blocks)
    poolmlp_kernel<<<NB, 256, 0, stream>>>(bufO, bat, Wm1, bm1, Wm2, bm2, out);
}

// Round 13
// 349.423 us; speedup vs baseline: 2.4503x; 1.0379x over previous
//
#include <hip/hip_runtime.h>
#include <hip/hip_bf16.h>

#define N_NODES 50000
#define N_EDGES 800000
#define ETOT    (N_EDGES + N_NODES)
#define NB      64
#define IN_C    128
#define HID     64
#define HEADS   4
#define F1      (HEADS * HID)   /* 256 */
#define NEG     0.2f
#define SCAN_NBLK ((N_NODES + 255) / 256)   /* 196 */

typedef __attribute__((ext_vector_type(8))) short  short8v;
typedef __attribute__((ext_vector_type(4))) float  float4v;

__device__ __forceinline__ float lrelu(float x) { return x >= 0.f ? x : NEG * x; }

// round-to-nearest-even f32 -> bf16 bits
__device__ __forceinline__ unsigned short f2bf(float f) {
    unsigned u = __float_as_uint(f);
    u += 0x7FFFu + ((u >> 16) & 1u);
    return (unsigned short)(u >> 16);
}
__device__ __forceinline__ float bf2f(unsigned short h) {
    return __uint_as_float(((unsigned)h) << 16);
}

// fragment-linear W index: lane l of fragment (kb, ng) reads bytes [l*16, l*16+16)
__device__ __forceinline__ int wf_idx(int k, int n) {
    return (((k >> 5) * 16 + (n >> 4)) << 9) + (((k >> 3) & 3) << 7) + ((n & 15) << 3) + (k & 7);
}

// ---------------- CSR build: degree count + (fused) W conversion to fragment layout ----
__global__ void deg_kernel(const int* __restrict__ ei, int* __restrict__ deg,
                           const float* __restrict__ W1,
                           unsigned short* __restrict__ W1h, unsigned short* __restrict__ W1l,
                           const float* __restrict__ W2,
                           unsigned short* __restrict__ W2h, unsigned short* __restrict__ W2l) {
    int e = blockIdx.x * 256 + threadIdx.x;
    const int N1 = IN_C * 256;
    if (e < N1) {
        int k = e >> 8, n = e & 255;
        float v = W1[e];
        unsigned short h = f2bf(v);
        int idx = wf_idx(k, n);
        W1h[idx] = h;
        W1l[idx] = f2bf(v - bf2f(h));
    } else if (e < N1 + F1 * 256) {
        int j = e - N1;
        int k = j >> 8, n = j & 255;
        float v = W2[j];
        unsigned short h = f2bf(v);
        int idx = wf_idx(k, n);
        W2h[idx] = h;
        W2l[idx] = f2bf(v - bf2f(h));
    }
    if (e >= ETOT) return;
    int d = (e < N_EDGES) ? ei[N_EDGES + e] : (e - N_EDGES);
    atomicAdd(&deg[d], 1);
}

// 3-phase grid-wide exclusive scan of deg[N_NODES] -> off[N_NODES+1]
__global__ void scan1_kernel(const int* __restrict__ deg, int* __restrict__ part) {
    __shared__ int sh[256];
    int t = threadIdx.x;
    int i = blockIdx.x * 256 + t;
    sh[t] = (i < N_NODES) ? deg[i] : 0;
    __syncthreads();
    #pragma unroll
    for (int o = 128; o; o >>= 1) {
        if (t < o) sh[t] += sh[t + o];
        __syncthreads();
    }
    if (t == 0) part[blockIdx.x] = sh[0];
}

__global__ void scan2_kernel(int* __restrict__ part, int* __restrict__ off) {
    __shared__ int sh[256];
    int t = threadIdx.x;
    int v = (t < SCAN_NBLK) ? part[t] : 0;
    sh[t] = v;
    __syncthreads();
    #pragma unroll
    for (int o = 1; o < 256; o <<= 1) {
        int u = (t >= o) ? sh[t - o] : 0;
        __syncthreads();
        sh[t] += u;
        __syncthreads();
    }
    if (t < SCAN_NBLK) part[t] = sh[t] - v;       // exclusive block base
    if (t == 255) off[N_NODES] = sh[255];
}

__global__ void scan3_kernel(int* __restrict__ deg, const int* __restrict__ part,
                             int* __restrict__ off) {
    __shared__ int sh[256];
    int t = threadIdx.x;
    int i = blockIdx.x * 256 + t;
    int v = (i < N_NODES) ? deg[i] : 0;
    sh[t] = v;
    __syncthreads();
    #pragma unroll
    for (int o = 1; o < 256; o <<= 1) {
        int u = (t >= o) ? sh[t - o] : 0;
        __syncthreads();
        sh[t] += u;
        __syncthreads();
    }
    if (i < N_NODES) {
        off[i] = part[blockIdx.x] + sh[t] - v;
        deg[i] = 0;                                // reuse as cursor
    }
}

__global__ void scatter_kernel(const int* __restrict__ ei, const int* __restrict__ off,
                               int* __restrict__ cursor, int* __restrict__ esrc) {
    int e = blockIdx.x * 256 + threadIdx.x;
    if (e >= ETOT) return;
    int s, d;
    if (e < N_EDGES) { s = ei[e]; d = ei[N_EDGES + e]; }
    else             { s = d = e - N_EDGES; }
    int pos = off[d] + atomicAdd(&cursor[d], 1);
    esrc[pos] = s;
}

// ---------------- barrier-free 2-product bf16 MFMA GEMM + fused alpha ----------------
// BM=64; A tile staged to LDS ONCE; B fragments read from fragment-linear Wf (L2).
// NEW: C epilogue staged through LDS (union w/ A-tile) -> coalesced ushort4 stores.
template <bool SPLIT_A, int K>
__global__ __launch_bounds__(256) void gemm_mfma(const float* __restrict__ Af32,
                                                 const unsigned short* __restrict__ Abg,
                                                 const unsigned short* __restrict__ Wfh,
                                                 const unsigned short* __restrict__ Wfl,
                                                 const float* __restrict__ a_s,
                                                 const float* __restrict__ a_d,
                                                 unsigned short* __restrict__ Cb,
                                                 float* __restrict__ asrcO,
                                                 float* __restrict__ adstO,
                                                 int M) {
    union SMem {
        unsigned short a[64][K + 8];   // A tile (64 x K bf16, +8 pad)
        float          c[32][260];     // C staging (32 rows x 256 f32, +4 pad, 16B-aligned rows)
    };
    __shared__ SMem sm;
    int t  = threadIdx.x;
    int m0 = blockIdx.x * 64;
    int w  = t >> 6, l = t & 63;
    int lr = l & 15, lk = (l >> 4) * 8;

    float asv[4], adv[4];
    #pragma unroll
    for (int nf = 0; nf < 4; ++nf) {
        asv[nf] = a_s[w * 64 + nf * 16 + lr];
        adv[nf] = a_d[w * 64 + nf * 16 + lr];
    }

    // ---- stage ENTIRE A tile (64 x K bf16), one barrier ----
    {
        int r = t >> 2, q = t & 3, gr = m0 + r;
        if (SPLIT_A) {
            #pragma unroll
            for (int c = 0; c < K / 4; c += 4) {
                int col = q * (K / 4) + c;
                float4 v = make_float4(0.f, 0.f, 0.f, 0.f);
                if (gr < M) v = *(const float4*)&Af32[(size_t)gr * K + col];
                ushort4 hi;
                hi.x = f2bf(v.x); hi.y = f2bf(v.y); hi.z = f2bf(v.z); hi.w = f2bf(v.w);
                *(ushort4*)&sm.a[r][col] = hi;
            }
        } else {
            #pragma unroll
            for (int c = 0; c < K / 4; c += 8) {
                int col = q * (K / 4) + c;
                short8v vh = {0,0,0,0,0,0,0,0};
                if (gr < M) vh = *(const short8v*)&Abg[(size_t)gr * K + col];
                *(short8v*)&sm.a[r][col] = vh;
            }
        }
    }
    __syncthreads();

    float4v acc[4][4];
    #pragma unroll
    for (int mf = 0; mf < 4; ++mf)
        #pragma unroll
        for (int nf = 0; nf < 4; ++nf)
            acc[mf][nf] = (float4v){0.f, 0.f, 0.f, 0.f};

    constexpr int KB = K / 32;
    #pragma unroll 2
    for (int kb = 0; kb < KB; ++kb) {
        short8v b_hf[4], b_lf[4];
        #pragma unroll
        for (int nf = 0; nf < 4; ++nf) {
            size_t bidx = (size_t)((kb * 16 + w * 4 + nf) * 512 + l * 8);
            b_hf[nf] = *(const short8v*)&Wfh[bidx];
            b_lf[nf] = *(const short8v*)&Wfl[bidx];
        }
        #pragma unroll
        for (int mf = 0; mf < 4; ++mf) {
            short8v a_f = *(short8v*)&sm.a[mf * 16 + lr][kb * 32 + lk];
            #pragma unroll
            for (int nf = 0; nf < 4; ++nf) {
                acc[mf][nf] = __builtin_amdgcn_mfma_f32_16x16x32_bf16(a_f, b_hf[nf], acc[mf][nf], 0, 0, 0);
                acc[mf][nf] = __builtin_amdgcn_mfma_f32_16x16x32_bf16(a_f, b_lf[nf], acc[mf][nf], 0, 0, 0);
            }
        }
    }

    // ---- fused alpha: per-row dot with a_s/a_d (head w), 16-lane reduce ----
    #pragma unroll
    for (int mf = 0; mf < 4; ++mf)
        #pragma unroll
        for (int r = 0; r < 4; ++r) {
            float ps = acc[mf][0][r] * asv[0] + acc[mf][1][r] * asv[1]
                     + acc[mf][2][r] * asv[2] + acc[mf][3][r] * asv[3];
            float pd = acc[mf][0][r] * adv[0] + acc[mf][1][r] * adv[1]
                     + acc[mf][2][r] * adv[2] + acc[mf][3][r] * adv[3];
            #pragma unroll
            for (int o = 8; o; o >>= 1) {
                ps += __shfl_xor(ps, o);
                pd += __shfl_xor(pd, o);
            }
            int gr = m0 + mf * 16 + (l >> 4) * 4 + r;
            if (lr == 0 && gr < M) {
                asrcO[gr * 4 + w] = ps;
                adstO[gr * 4 + w] = pd;
            }
        }

    // ---- C epilogue via LDS: two 32-row halves, coalesced bf16 stores ----
    #pragma unroll
    for (int half = 0; half < 2; ++half) {
        __syncthreads();   // A-tile reads (or previous readback) complete
        #pragma unroll
        for (int mf2 = 0; mf2 < 2; ++mf2) {
            int mf = half * 2 + mf2;
            #pragma unroll
            for (int nf = 0; nf < 4; ++nf)
                #pragma unroll
                for (int r = 0; r < 4; ++r)
                    sm.c[mf2 * 16 + (l >> 4) * 4 + r][w * 64 + nf * 16 + lr] = acc[mf][nf][r];
        }
        __syncthreads();
        #pragma unroll
        for (int p = 0; p < 8; ++p) {
            int idx = t + p * 256;          // 0..2047: 32 rows x 64 ushort4 chunks
            int row = idx >> 6, c4 = (idx & 63) * 4;
            int gr = m0 + half * 32 + row;
            if (gr < M) {
                float4 v = *(const float4*)&sm.c[row][c4];
                ushort4 hv;
                hv.x = f2bf(v.x); hv.y = f2bf(v.y); hv.z = f2bf(v.z); hv.w = f2bf(v.w);
                *(ushort4*)&Cb[(size_t)gr * F1 + c4] = hv;
            }
        }
    }
}

// ---------------- fused segment softmax + aggregation (one wave per dst node) ----------------
// Lane owns channels lane*4..lane*4+3 (head lane>>4): ONE ushort4 gather per edge.
// LAYER 1: out = bf16 relu(agg + bias); LAYER 2: f32 head-mean + bias.
template <int LAYER>
__global__ void agg_kernel(const unsigned short* __restrict__ hb,
                           const float* __restrict__ asrc,
                           const float* __restrict__ adst,
                           const int* __restrict__ off,
                           const int* __restrict__ esrc,
                           const float* __restrict__ bias,
                           float* __restrict__ outF,
                           unsigned short* __restrict__ oh) {
    __shared__ int   soff[64];            // precomputed byte offsets s*512
    __shared__ float cf[64][4];
    int d    = blockIdx.x;
    int lane = threadIdx.x;  // 64 = 1 wave
    int w    = lane >> 4;    // this lane's head
    int e0 = off[d], e1 = off[d + 1];
    float4 ad = *(const float4*)(adst + (size_t)d * 4);
    float den = 0.f;
    float a0 = 0.f, a1 = 0.f, a2 = 0.f, a3 = 0.f;
    const char* hbase = (const char*)hb;
    int lb = lane * 8;                    // this lane's byte offset within a row

    for (int base = e0; base < e1; base += 64) {
        int cnt = min(64, e1 - base);
        if (lane < cnt) {
            int s = esrc[base + lane];
            soff[lane] = s * (F1 * 2);
            float4 as = *(const float4*)(asrc + (size_t)s * 4);
            cf[lane][0] = __expf(lrelu(as.x + ad.x));
            cf[lane][1] = __expf(lrelu(as.y + ad.y));
            cf[lane][2] = __expf(lrelu(as.z + ad.z));
            cf[lane][3] = __expf(lrelu(as.w + ad.w));
        }
        __syncthreads();
        int i = 0;
        for (; i + 4 <= cnt; i += 4) {
            int o0 = soff[i], o1 = soff[i + 1], o2 = soff[i + 2], o3 = soff[i + 3];
            ushort4 h0 = *(const ushort4*)(hbase + o0 + lb);
            ushort4 h1 = *(const ushort4*)(hbase + o1 + lb);
            ushort4 h2 = *(const ushort4*)(hbase + o2 + lb);
            ushort4 h3 = *(const ushort4*)(hbase + o3 + lb);
            float c0 = cf[i][w], c1 = cf[i + 1][w], c2 = cf[i + 2][w], c3 = cf[i + 3][w];
            den += (c0 + c1) + (c2 + c3);
            a0 += c0 * bf2f(h0.x) + c1 * bf2f(h1.x) + c2 * bf2f(h2.x) + c3 * bf2f(h3.x);
            a1 += c0 * bf2f(h0.y) + c1 * bf2f(h1.y) + c2 * bf2f(h2.y) + c3 * bf2f(h3.y);
            a2 += c0 * bf2f(h0.z) + c1 * bf2f(h1.z) + c2 * bf2f(h2.z) + c3 * bf2f(h3.z);
            a3 += c0 * bf2f(h0.w) + c1 * bf2f(h1.w) + c2 * bf2f(h2.w) + c3 * bf2f(h3.w);
        }
        for (; i < cnt; ++i) {
            int o = soff[i];
            float c = cf[i][w];
            ushort4 hv = *(const ushort4*)(hbase + o + lb);
            den += c;
            a0 += c * bf2f(hv.x);
            a1 += c * bf2f(hv.y);
            a2 += c * bf2f(hv.z);
            a3 += c * bf2f(hv.w);
        }
        __syncthreads();
    }

    float r = 1.f / fmaxf(den, 1e-16f);
    if (LAYER == 1) {
        ushort4 hi;
        hi.x = f2bf(fmaxf(a0 * r + bias[lane * 4 + 0], 0.f));
        hi.y = f2bf(fmaxf(a1 * r + bias[lane * 4 + 1], 0.f));
        hi.z = f2bf(fmaxf(a2 * r + bias[lane * 4 + 2], 0.f));
        hi.w = f2bf(fmaxf(a3 * r + bias[lane * 4 + 3], 0.f));
        *(ushort4*)&oh[(size_t)d * F1 + lane * 4] = hi;
    } else {
        float v0 = a0 * r, v1 = a1 * r, v2 = a2 * r, v3 = a3 * r;
        // head-mean: lanes {L, L^16, L^32, L^48} hold same hid for heads 0..3
        v0 += __shfl_xor(v0, 16); v0 += __shfl_xor(v0, 32);
        v1 += __shfl_xor(v1, 16); v1 += __shfl_xor(v1, 32);
        v2 += __shfl_xor(v2, 16); v2 += __shfl_xor(v2, 32);
        v3 += __shfl_xor(v3, 16); v3 += __shfl_xor(v3, 32);
        if (lane < 16) {
            float4 o;
            o.x = 0.25f * v0 + bias[lane * 4 + 0];
            o.y = 0.25f * v1 + bias[lane * 4 + 1];
            o.z = 0.25f * v2 + bias[lane * 4 + 2];
            o.w = 0.25f * v3 + bias[lane * 4 + 3];
            *(float4*)&outF[(size_t)d * HID + lane * 4] = o;
        }
    }
}

// ---------------- fused global mean pool + graph MLP: one block per graph ----------------
__device__ __forceinline__ int lowerb(const int* __restrict__ a, int n, int v) {
    int lo = 0, hi = n;
    while (lo < hi) { int m = (lo + hi) >> 1; if (a[m] < v) lo = m + 1; else hi = m; }
    return lo;
}

__global__ void poolmlp_kernel(const float* __restrict__ h2,
                               const int* __restrict__ batch,
                               const float* __restrict__ Wm1, const float* __restrict__ bm1,
                               const float* __restrict__ Wm2, const float* __restrict__ bm2,
                               float* __restrict__ out) {
    __shared__ float sh[4][HID];
    int b = blockIdx.x;
    int t = threadIdx.x, w = t >> 6, c = t & 63;
    int lo = lowerb(batch, N_NODES, b);
    int hi = lowerb(batch, N_NODES, b + 1);
    float s = 0.f;
    for (int n = lo + w; n < hi; n += 4) s += h2[(size_t)n * HID + c];
    sh[w][c] = s;
    __syncthreads();
    if (w == 0) {
        float inv = 1.f / fmaxf((float)(hi - lo), 1.f);
        float P = (sh[0][c] + sh[1][c] + sh[2][c] + sh[3][c]) * inv;
        sh[0][c] = P;
        float s1 = bm1[c];
        #pragma unroll
        for (int k = 0; k < HID; ++k) s1 += sh[0][k] * Wm1[k * HID + c];
        float r = fmaxf(s1, 0.f) * Wm2[c];
        #pragma unroll
        for (int o = 32; o; o >>= 1) r += __shfl_xor(r, o);
        if (c == 0) out[b] = r + bm2[0];
    }
}

extern "C" void kernel_launch(void* const* d_in, const int* in_sizes, int n_in,
                              void* d_out, int out_size, void* d_ws, size_t ws_size,
                              hipStream_t stream) {
    const float* x   = (const float*)d_in[0];
    const int*   ei  = (const int*)d_in[1];
    const int*   bat = (const int*)d_in[2];
    const float* W1  = (const float*)d_in[3];
    const float* as1 = (const float*)d_in[4];
    const float* ad1 = (const float*)d_in[5];
    const float* b1  = (const float*)d_in[6];
    const float* W2  = (const float*)d_in[7];
    const float* as2 = (const float*)d_in[8];
    const float* ad2 = (const float*)d_in[9];
    const float* b2  = (const float*)d_in[10];
    const float* Wm1 = (const float*)d_in[11];
    const float* bm1 = (const float*)d_in[12];
    const float* Wm2 = (const float*)d_in[13];
    const float* bm2 = (const float*)d_in[14];
    float* out = (float*)d_out;

    char* ws = (char*)d_ws;
    size_t cursor = 0;
    auto alloc = [&](size_t bytes) {
        void* p = ws + cursor;
        cursor += (bytes + 511) & ~(size_t)511;
        return p;
    };
    int*   deg    = (int*)alloc((size_t)N_NODES * 4);
    int*   off    = (int*)alloc((size_t)(N_NODES + 1) * 4);
    int*   part   = (int*)alloc((size_t)SCAN_NBLK * 4);
    int*   esrc   = (int*)alloc((size_t)ETOT * 4);
    unsigned short* bufHb = (unsigned short*)alloc((size_t)N_NODES * F1 * 2);  // gemm bf16 out
    // union region: oh (agg1 bf16 out) / bufO (agg2 f32 out) alias
    char*  U      = (char*)alloc((size_t)N_NODES * F1 * 4);
    unsigned short* oh = (unsigned short*)U;
    float* bufO   = (float*)U;
    float* asrc   = (float*)alloc((size_t)N_NODES * HEADS * 4);
    float* adst   = (float*)alloc((size_t)N_NODES * HEADS * 4);
    unsigned short* W1th = (unsigned short*)alloc((size_t)256 * IN_C * 2);
    unsigned short* W1tl = (unsigned short*)alloc((size_t)256 * IN_C * 2);
    unsigned short* W2th = (unsigned short*)alloc((size_t)256 * F1 * 2);
    unsigned short* W2tl = (unsigned short*)alloc((size_t)256 * F1 * 2);

    hipMemsetAsync(deg, 0, (size_t)N_NODES * 4, stream);

    deg_kernel<<<(ETOT + 255) / 256, 256, 0, stream>>>(ei, deg, W1, W1th, W1tl,
                                                       W2, W2th, W2tl);
    scan1_kernel<<<SCAN_NBLK, 256, 0, stream>>>(deg, part);
    scan2_kernel<<<1, 256, 0, stream>>>(part, off);
    scan3_kernel<<<SCAN_NBLK, 256, 0, stream>>>(deg, part, off);
    scatter_kernel<<<(ETOT + 255) / 256, 256, 0, stream>>>(ei, off, deg, esrc);

    const int GB = (N_NODES + 63) / 64;
    // layer 1 (gemm writes bf16 h + alpha_src/dst; agg gathers bf16, emits bf16)
    gemm_mfma<true, IN_C><<<GB, 256, 0, stream>>>(x, nullptr, W1th, W1tl,
                                                  as1, ad1, bufHb, asrc, adst, N_NODES);
    agg_kernel<1><<<N_NODES, 64, 0, stream>>>(bufHb, asrc, adst, off, esrc, b1,
                                              nullptr, oh);

    // layer 2
    gemm_mfma<false, F1><<<GB, 256, 0, stream>>>(nullptr, oh, W2th, W2tl,
                                                 as2, ad2, bufHb, asrc, adst, N_NODES);
    agg_kernel<2><<<N_NODES, 64, 0, stream>>>(bufHb, asrc, adst, off, esrc, b2,
                                              bufO, nullptr);

    // fused pool + MLP (batch sorted -> binary-search ranges; 64 blocks)
    poolmlp_kernel<<<NB, 256, 0, stream>>>(bufO, bat, Wm1, bm1, Wm2, bm2, out);
}

// Round 14
// 341.927 us; speedup vs baseline: 2.5040x; 1.0219x over previous
//
#include <hip/hip_runtime.h>
#include <hip/hip_bf16.h>

#define N_NODES 50000
#define N_EDGES 800000
#define ETOT    (N_EDGES + N_NODES)
#define NB      64
#define IN_C    128
#define HID     64
#define HEADS   4
#define F1      (HEADS * HID)   /* 256 */
#define NEG     0.2f
#define SCAN_NBLK ((N_NODES + 255) / 256)   /* 196 */

typedef __attribute__((ext_vector_type(8))) short  short8v;
typedef __attribute__((ext_vector_type(4))) float  float4v;

__device__ __forceinline__ float lrelu(float x) { return x >= 0.f ? x : NEG * x; }

// round-to-nearest-even f32 -> bf16 bits
__device__ __forceinline__ unsigned short f2bf(float f) {
    unsigned u = __float_as_uint(f);
    u += 0x7FFFu + ((u >> 16) & 1u);
    return (unsigned short)(u >> 16);
}
__device__ __forceinline__ float bf2f(unsigned short h) {
    return __uint_as_float(((unsigned)h) << 16);
}

// fragment-linear W index: lane l of fragment (kb, ng) reads bytes [l*16, l*16+16)
__device__ __forceinline__ int wf_idx(int k, int n) {
    return (((k >> 5) * 16 + (n >> 4)) << 9) + (((k >> 3) & 3) << 7) + ((n & 15) << 3) + (k & 7);
}

// ---------------- CSR build: degree count + (fused) W conversion to fragment layout ----
__global__ void deg_kernel(const int* __restrict__ ei, int* __restrict__ deg,
                           const float* __restrict__ W1,
                           unsigned short* __restrict__ W1h, unsigned short* __restrict__ W1l,
                           const float* __restrict__ W2,
                           unsigned short* __restrict__ W2h, unsigned short* __restrict__ W2l) {
    int e = blockIdx.x * 256 + threadIdx.x;
    const int N1 = IN_C * 256;
    if (e < N1) {
        int k = e >> 8, n = e & 255;
        float v = W1[e];
        unsigned short h = f2bf(v);
        int idx = wf_idx(k, n);
        W1h[idx] = h;
        W1l[idx] = f2bf(v - bf2f(h));
    } else if (e < N1 + F1 * 256) {
        int j = e - N1;
        int k = j >> 8, n = j & 255;
        float v = W2[j];
        unsigned short h = f2bf(v);
        int idx = wf_idx(k, n);
        W2h[idx] = h;
        W2l[idx] = f2bf(v - bf2f(h));
    }
    if (e >= ETOT) return;
    int d = (e < N_EDGES) ? ei[N_EDGES + e] : (e - N_EDGES);
    atomicAdd(&deg[d], 1);
}

// 3-phase grid-wide exclusive scan of deg[N_NODES] -> off[N_NODES+1]
__global__ void scan1_kernel(const int* __restrict__ deg, int* __restrict__ part) {
    __shared__ int sh[256];
    int t = threadIdx.x;
    int i = blockIdx.x * 256 + t;
    sh[t] = (i < N_NODES) ? deg[i] : 0;
    __syncthreads();
    #pragma unroll
    for (int o = 128; o; o >>= 1) {
        if (t < o) sh[t] += sh[t + o];
        __syncthreads();
    }
    if (t == 0) part[blockIdx.x] = sh[0];
}

__global__ void scan2_kernel(int* __restrict__ part, int* __restrict__ off) {
    __shared__ int sh[256];
    int t = threadIdx.x;
    int v = (t < SCAN_NBLK) ? part[t] : 0;
    sh[t] = v;
    __syncthreads();
    #pragma unroll
    for (int o = 1; o < 256; o <<= 1) {
        int u = (t >= o) ? sh[t - o] : 0;
        __syncthreads();
        sh[t] += u;
        __syncthreads();
    }
    if (t < SCAN_NBLK) part[t] = sh[t] - v;       // exclusive block base
    if (t == 255) off[N_NODES] = sh[255];
}

__global__ void scan3_kernel(int* __restrict__ deg, const int* __restrict__ part,
                             int* __restrict__ off) {
    __shared__ int sh[256];
    int t = threadIdx.x;
    int i = blockIdx.x * 256 + t;
    int v = (i < N_NODES) ? deg[i] : 0;
    sh[t] = v;
    __syncthreads();
    #pragma unroll
    for (int o = 1; o < 256; o <<= 1) {
        int u = (t >= o) ? sh[t - o] : 0;
        __syncthreads();
        sh[t] += u;
        __syncthreads();
    }
    if (i < N_NODES) {
        off[i] = part[blockIdx.x] + sh[t] - v;
        deg[i] = 0;                                // reuse as cursor
    }
}

__global__ void scatter_kernel(const int* __restrict__ ei, const int* __restrict__ off,
                               int* __restrict__ cursor, int* __restrict__ esrc) {
    int e = blockIdx.x * 256 + threadIdx.x;
    if (e >= ETOT) return;
    int s, d;
    if (e < N_EDGES) { s = ei[e]; d = ei[N_EDGES + e]; }
    else             { s = d = e - N_EDGES; }
    int pos = off[d] + atomicAdd(&cursor[d], 1);
    esrc[pos] = s;
}

// ---------------- LDS-free-A 2-product bf16 MFMA GEMM + fused alpha ----------------
// BM=64; A fragments read DIRECTLY from global (L1-served, 4-wave reuse of 17-34KB);
// B fragments from fragment-linear Wf (L2). Barrier-free K loop; LDS only for the
// coalesced C epilogue. Occupancy VGPR-bound (~3 blocks/CU).
template <bool SPLIT_A, int K>
__global__ __launch_bounds__(256) void gemm_mfma(const float* __restrict__ Af32,
                                                 const unsigned short* __restrict__ Abg,
                                                 const unsigned short* __restrict__ Wfh,
                                                 const unsigned short* __restrict__ Wfl,
                                                 const float* __restrict__ a_s,
                                                 const float* __restrict__ a_d,
                                                 unsigned short* __restrict__ Cb,
                                                 float* __restrict__ asrcO,
                                                 float* __restrict__ adstO,
                                                 int M) {
    __shared__ float smc[32][260];   // C staging (32 rows x 256 f32, +4 pad)
    int t  = threadIdx.x;
    int m0 = blockIdx.x * 64;
    int w  = t >> 6, l = t & 63;
    int lr = l & 15, lk = (l >> 4) * 8;

    float asv[4], adv[4];
    #pragma unroll
    for (int nf = 0; nf < 4; ++nf) {
        asv[nf] = a_s[w * 64 + nf * 16 + lr];
        adv[nf] = a_d[w * 64 + nf * 16 + lr];
    }

    float4v acc[4][4];
    #pragma unroll
    for (int mf = 0; mf < 4; ++mf)
        #pragma unroll
        for (int nf = 0; nf < 4; ++nf)
            acc[mf][nf] = (float4v){0.f, 0.f, 0.f, 0.f};

    constexpr int KB = K / 32;
    #pragma unroll 2
    for (int kb = 0; kb < KB; ++kb) {
        short8v b_hf[4], b_lf[4];
        #pragma unroll
        for (int nf = 0; nf < 4; ++nf) {
            size_t bidx = (size_t)((kb * 16 + w * 4 + nf) * 512 + l * 8);
            b_hf[nf] = *(const short8v*)&Wfh[bidx];
            b_lf[nf] = *(const short8v*)&Wfl[bidx];
        }
        short8v a_f[4];
        #pragma unroll
        for (int mf = 0; mf < 4; ++mf) {
            int gr = m0 + mf * 16 + lr;
            if (SPLIT_A) {
                float4 v0 = make_float4(0.f, 0.f, 0.f, 0.f), v1 = v0;
                if (gr < M) {
                    const float* ap = &Af32[(size_t)gr * K + kb * 32 + lk];
                    v0 = *(const float4*)ap;
                    v1 = *(const float4*)(ap + 4);
                }
                short8v a;
                a[0] = (short)f2bf(v0.x); a[1] = (short)f2bf(v0.y);
                a[2] = (short)f2bf(v0.z); a[3] = (short)f2bf(v0.w);
                a[4] = (short)f2bf(v1.x); a[5] = (short)f2bf(v1.y);
                a[6] = (short)f2bf(v1.z); a[7] = (short)f2bf(v1.w);
                a_f[mf] = a;
            } else {
                short8v a = {0,0,0,0,0,0,0,0};
                if (gr < M) a = *(const short8v*)&Abg[(size_t)gr * K + kb * 32 + lk];
                a_f[mf] = a;
            }
        }
        #pragma unroll
        for (int mf = 0; mf < 4; ++mf)
            #pragma unroll
            for (int nf = 0; nf < 4; ++nf) {
                acc[mf][nf] = __builtin_amdgcn_mfma_f32_16x16x32_bf16(a_f[mf], b_hf[nf], acc[mf][nf], 0, 0, 0);
                acc[mf][nf] = __builtin_amdgcn_mfma_f32_16x16x32_bf16(a_f[mf], b_lf[nf], acc[mf][nf], 0, 0, 0);
            }
    }

    // ---- fused alpha: per-row dot with a_s/a_d (head w), 16-lane reduce ----
    #pragma unroll
    for (int mf = 0; mf < 4; ++mf)
        #pragma unroll
        for (int r = 0; r < 4; ++r) {
            float ps = acc[mf][0][r] * asv[0] + acc[mf][1][r] * asv[1]
                     + acc[mf][2][r] * asv[2] + acc[mf][3][r] * asv[3];
            float pd = acc[mf][0][r] * adv[0] + acc[mf][1][r] * adv[1]
                     + acc[mf][2][r] * adv[2] + acc[mf][3][r] * adv[3];
            #pragma unroll
            for (int o = 8; o; o >>= 1) {
                ps += __shfl_xor(ps, o);
                pd += __shfl_xor(pd, o);
            }
            int gr = m0 + mf * 16 + (l >> 4) * 4 + r;
            if (lr == 0 && gr < M) {
                asrcO[gr * 4 + w] = ps;
                adstO[gr * 4 + w] = pd;
            }
        }

    // ---- C epilogue via LDS: two 32-row halves, coalesced bf16 stores ----
    #pragma unroll
    for (int half = 0; half < 2; ++half) {
        __syncthreads();
        #pragma unroll
        for (int mf2 = 0; mf2 < 2; ++mf2) {
            int mf = half * 2 + mf2;
            #pragma unroll
            for (int nf = 0; nf < 4; ++nf)
                #pragma unroll
                for (int r = 0; r < 4; ++r)
                    smc[mf2 * 16 + (l >> 4) * 4 + r][w * 64 + nf * 16 + lr] = acc[mf][nf][r];
        }
        __syncthreads();
        #pragma unroll
        for (int p = 0; p < 8; ++p) {
            int idx = t + p * 256;          // 0..2047: 32 rows x 64 ushort4 chunks
            int row = idx >> 6, c4 = (idx & 63) * 4;
            int gr = m0 + half * 32 + row;
            if (gr < M) {
                float4 v = *(const float4*)&smc[row][c4];
                ushort4 hv;
                hv.x = f2bf(v.x); hv.y = f2bf(v.y); hv.z = f2bf(v.z); hv.w = f2bf(v.w);
                *(ushort4*)&Cb[(size_t)gr * F1 + c4] = hv;
            }
        }
    }
}

// ---------------- fused segment softmax + aggregation (one wave per dst node) ----------------
// Lane owns channels lane*4..lane*4+3 (head lane>>4): ONE ushort4 gather per edge.
// LAYER 1: out = bf16 relu(agg + bias); LAYER 2: f32 head-mean + bias.
template <int LAYER>
__global__ void agg_kernel(const unsigned short* __restrict__ hb,
                           const float* __restrict__ asrc,
                           const float* __restrict__ adst,
                           const int* __restrict__ off,
                           const int* __restrict__ esrc,
                           const float* __restrict__ bias,
                           float* __restrict__ outF,
                           unsigned short* __restrict__ oh) {
    __shared__ int   soff[64];            // precomputed byte offsets s*512
    __shared__ float cf[64][4];
    int d    = blockIdx.x;
    int lane = threadIdx.x;  // 64 = 1 wave
    int w    = lane >> 4;    // this lane's head
    int e0 = off[d], e1 = off[d + 1];
    float4 ad = *(const float4*)(adst + (size_t)d * 4);
    float den = 0.f;
    float a0 = 0.f, a1 = 0.f, a2 = 0.f, a3 = 0.f;
    const char* hbase = (const char*)hb;
    int lb = lane * 8;                    // this lane's byte offset within a row

    for (int base = e0; base < e1; base += 64) {
        int cnt = min(64, e1 - base);
        if (lane < cnt) {
            int s = esrc[base + lane];
            soff[lane] = s * (F1 * 2);
            float4 as = *(const float4*)(asrc + (size_t)s * 4);
            cf[lane][0] = __expf(lrelu(as.x + ad.x));
            cf[lane][1] = __expf(lrelu(as.y + ad.y));
            cf[lane][2] = __expf(lrelu(as.z + ad.z));
            cf[lane][3] = __expf(lrelu(as.w + ad.w));
        }
        __syncthreads();
        int i = 0;
        for (; i + 4 <= cnt; i += 4) {
            int o0 = soff[i], o1 = soff[i + 1], o2 = soff[i + 2], o3 = soff[i + 3];
            ushort4 h0 = *(const ushort4*)(hbase + o0 + lb);
            ushort4 h1 = *(const ushort4*)(hbase + o1 + lb);
            ushort4 h2 = *(const ushort4*)(hbase + o2 + lb);
            ushort4 h3 = *(const ushort4*)(hbase + o3 + lb);
            float c0 = cf[i][w], c1 = cf[i + 1][w], c2 = cf[i + 2][w], c3 = cf[i + 3][w];
            den += (c0 + c1) + (c2 + c3);
            a0 += c0 * bf2f(h0.x) + c1 * bf2f(h1.x) + c2 * bf2f(h2.x) + c3 * bf2f(h3.x);
            a1 += c0 * bf2f(h0.y) + c1 * bf2f(h1.y) + c2 * bf2f(h2.y) + c3 * bf2f(h3.y);
            a2 += c0 * bf2f(h0.z) + c1 * bf2f(h1.z) + c2 * bf2f(h2.z) + c3 * bf2f(h3.z);
            a3 += c0 * bf2f(h0.w) + c1 * bf2f(h1.w) + c2 * bf2f(h2.w) + c3 * bf2f(h3.w);
        }
        for (; i < cnt; ++i) {
            int o = soff[i];
            float c = cf[i][w];
            ushort4 hv = *(const ushort4*)(hbase + o + lb);
            den += c;
            a0 += c * bf2f(hv.x);
            a1 += c * bf2f(hv.y);
            a2 += c * bf2f(hv.z);
            a3 += c * bf2f(hv.w);
        }
        __syncthreads();
    }

    float r = 1.f / fmaxf(den, 1e-16f);
    if (LAYER == 1) {
        ushort4 hi;
        hi.x = f2bf(fmaxf(a0 * r + bias[lane * 4 + 0], 0.f));
        hi.y = f2bf(fmaxf(a1 * r + bias[lane * 4 + 1], 0.f));
        hi.z = f2bf(fmaxf(a2 * r + bias[lane * 4 + 2], 0.f));
        hi.w = f2bf(fmaxf(a3 * r + bias[lane * 4 + 3], 0.f));
        *(ushort4*)&oh[(size_t)d * F1 + lane * 4] = hi;
    } else {
        float v0 = a0 * r, v1 = a1 * r, v2 = a2 * r, v3 = a3 * r;
        // head-mean: lanes {L, L^16, L^32, L^48} hold same hid for heads 0..3
        v0 += __shfl_xor(v0, 16); v0 += __shfl_xor(v0, 32);
        v1 += __shfl_xor(v1, 16); v1 += __shfl_xor(v1, 32);
        v2 += __shfl_xor(v2, 16); v2 += __shfl_xor(v2, 32);
        v3 += __shfl_xor(v3, 16); v3 += __shfl_xor(v3, 32);
        if (lane < 16) {
            float4 o;
            o.x = 0.25f * v0 + bias[lane * 4 + 0];
            o.y = 0.25f * v1 + bias[lane * 4 + 1];
            o.z = 0.25f * v2 + bias[lane * 4 + 2];
            o.w = 0.25f * v3 + bias[lane * 4 + 3];
            *(float4*)&outF[(size_t)d * HID + lane * 4] = o;
        }
    }
}

// ---------------- fused global mean pool + graph MLP: one block per graph ----------------
__device__ __forceinline__ int lowerb(const int* __restrict__ a, int n, int v) {
    int lo = 0, hi = n;
    while (lo < hi) { int m = (lo + hi) >> 1; if (a[m] < v) lo = m + 1; else hi = m; }
    return lo;
}

__global__ void poolmlp_kernel(const float* __restrict__ h2,
                               const int* __restrict__ batch,
                               const float* __restrict__ Wm1, const float* __restrict__ bm1,
                               const float* __restrict__ Wm2, const float* __restrict__ bm2,
                               float* __restrict__ out) {
    __shared__ float sh[4][HID];
    int b = blockIdx.x;
    int t = threadIdx.x, w = t >> 6, c = t & 63;
    int lo = lowerb(batch, N_NODES, b);
    int hi = lowerb(batch, N_NODES, b + 1);
    float s = 0.f;
    for (int n = lo + w; n < hi; n += 4) s += h2[(size_t)n * HID + c];
    sh[w][c] = s;
    __syncthreads();
    if (w == 0) {
        float inv = 1.f / fmaxf((float)(hi - lo), 1.f);
        float P = (sh[0][c] + sh[1][c] + sh[2][c] + sh[3][c]) * inv;
        sh[0][c] = P;
        float s1 = bm1[c];
        #pragma unroll
        for (int k = 0; k < HID; ++k) s1 += sh[0][k] * Wm1[k * HID + c];
        float r = fmaxf(s1, 0.f) * Wm2[c];
        #pragma unroll
        for (int o = 32; o; o >>= 1) r += __shfl_xor(r, o);
        if (c == 0) out[b] = r + bm2[0];
    }
}

extern "C" void kernel_launch(void* const* d_in, const int* in_sizes, int n_in,
                              void* d_out, int out_size, void* d_ws, size_t ws_size,
                              hipStream_t stream) {
    const float* x   = (const float*)d_in[0];
    const int*   ei  = (const int*)d_in[1];
    const int*   bat = (const int*)d_in[2];
    const float* W1  = (const float*)d_in[3];
    const float* as1 = (const float*)d_in[4];
    const float* ad1 = (const float*)d_in[5];
    const float* b1  = (const float*)d_in[6];
    const float* W2  = (const float*)d_in[7];
    const float* as2 = (const float*)d_in[8];
    const float* ad2 = (const float*)d_in[9];
    const float* b2  = (const float*)d_in[10];
    const float* Wm1 = (const float*)d_in[11];
    const float* bm1 = (const float*)d_in[12];
    const float* Wm2 = (const float*)d_in[13];
    const float* bm2 = (const float*)d_in[14];
    float* out = (float*)d_out;

    char* ws = (char*)d_ws;
    size_t cursor = 0;
    auto alloc = [&](size_t bytes) {
        void* p = ws + cursor;
        cursor += (bytes + 511) & ~(size_t)511;
        return p;
    };
    int*   deg    = (int*)alloc((size_t)N_NODES * 4);
    int*   off    = (int*)alloc((size_t)(N_NODES + 1) * 4);
    int*   part   = (int*)alloc((size_t)SCAN_NBLK * 4);
    int*   esrc   = (int*)alloc((size_t)ETOT * 4);
    unsigned short* bufHb = (unsigned short*)alloc((size_t)N_NODES * F1 * 2);  // gemm bf16 out
    // union region: oh (agg1 bf16 out) / bufO (agg2 f32 out) alias
    char*  U      = (char*)alloc((size_t)N_NODES * F1 * 4);
    unsigned short* oh = (unsigned short*)U;
    float* bufO   = (float*)U;
    float* asrc   = (float*)alloc((size_t)N_NODES * HEADS * 4);
    float* adst   = (float*)alloc((size_t)N_NODES * HEADS * 4);
    unsigned short* W1th = (unsigned short*)alloc((size_t)256 * IN_C * 2);
    unsigned short* W1tl = (unsigned short*)alloc((size_t)256 * IN_C * 2);
    unsigned short* W2th = (unsigned short*)alloc((size_t)256 * F1 * 2);
    unsigned short* W2tl = (unsigned short*)alloc((size_t)256 * F1 * 2);

    hipMemsetAsync(deg, 0, (size_t)N_NODES * 4, stream);

    deg_kernel<<<(ETOT + 255) / 256, 256, 0, stream>>>(ei, deg, W1, W1th, W1tl,
                                                       W2, W2th, W2tl);
    scan1_kernel<<<SCAN_NBLK, 256, 0, stream>>>(deg, part);
    scan2_kernel<<<1, 256, 0, stream>>>(part, off);
    scan3_kernel<<<SCAN_NBLK, 256, 0, stream>>>(deg, part, off);
    scatter_kernel<<<(ETOT + 255) / 256, 256, 0, stream>>>(ei, off, deg, esrc);

    const int GB = (N_NODES + 63) / 64;
    // layer 1 (gemm writes bf16 h + alpha_src/dst; agg gathers bf16, emits bf16)
    gemm_mfma<true, IN_C><<<GB, 256, 0, stream>>>(x, nullptr, W1th, W1tl,
                                                  as1, ad1, bufHb, asrc, adst, N_NODES);
    agg_kernel<1><<<N_NODES, 64, 0, stream>>>(bufHb, asrc, adst, off, esrc, b1,
                                              nullptr, oh);

    // layer 2
    gemm_mfma<false, F1><<<GB, 256, 0, stream>>>(nullptr, oh, W2th, W2tl,
                                                 as2, ad2, bufHb, asrc, adst, N_NODES);
    agg_kernel<2><<<N_NODES, 64, 0, stream>>>(bufHb, asrc, adst, off, esrc, b2,
                                              bufO, nullptr);

    // fused pool + MLP (batch sorted -> binary-search ranges; 64 blocks)
    poolmlp_kernel<<<NB, 256, 0, stream>>>(bufO, bat, Wm1, bm1, Wm2, bm2, out);
}

// Round 15
// 335.465 us; speedup vs baseline: 2.5522x; 1.0193x over previous
//
#include <hip/hip_runtime.h>
#include <hip/hip_bf16.h>

#define N_NODES 50000
#define N_EDGES 800000
#define ETOT    (N_EDGES + N_NODES)
#define NB      64
#define IN_C    128
#define HID     64
#define HEADS   4
#define F1      (HEADS * HID)   /* 256 */
#define NEG     0.2f
#define SCAN_NBLK ((N_NODES + 255) / 256)   /* 196 */

typedef __attribute__((ext_vector_type(8))) short  short8v;
typedef __attribute__((ext_vector_type(4))) float  float4v;

__device__ __forceinline__ float lrelu(float x) { return x >= 0.f ? x : NEG * x; }

__device__ __forceinline__ unsigned short f2bf(float f) {
    unsigned u = __float_as_uint(f);
    u += 0x7FFFu + ((u >> 16) & 1u);
    return (unsigned short)(u >> 16);
}
__device__ __forceinline__ float bf2f(unsigned short h) {
    return __uint_as_float(((unsigned)h) << 16);
}

// wave-local LDS fence (intra-wave producer->consumer; no block barrier)
__device__ __forceinline__ void wave_lds_fence() {
    asm volatile("s_waitcnt lgkmcnt(0)" ::: "memory");
}

// fragment-linear W index: lane l of fragment (kb, ng) reads bytes [l*16, l*16+16)
__device__ __forceinline__ int wf_idx(int k, int n) {
    return (((k >> 5) * 16 + (n >> 4)) << 9) + (((k >> 3) & 3) << 7) + ((n & 15) << 3) + (k & 7);
}

// ---------------- CSR build: degree count + (fused) W conversion to fragment layout ----
__global__ void deg_kernel(const int* __restrict__ ei, int* __restrict__ deg,
                           const float* __restrict__ W1,
                           unsigned short* __restrict__ W1h, unsigned short* __restrict__ W1l,
                           const float* __restrict__ W2,
                           unsigned short* __restrict__ W2h, unsigned short* __restrict__ W2l) {
    int e = blockIdx.x * 256 + threadIdx.x;
    const int N1 = IN_C * 256;
    if (e < N1) {
        int k = e >> 8, n = e & 255;
        float v = W1[e];
        unsigned short h = f2bf(v);
        int idx = wf_idx(k, n);
        W1h[idx] = h;
        W1l[idx] = f2bf(v - bf2f(h));
    } else if (e < N1 + F1 * 256) {
        int j = e - N1;
        int k = j >> 8, n = j & 255;
        float v = W2[j];
        unsigned short h = f2bf(v);
        int idx = wf_idx(k, n);
        W2h[idx] = h;
        W2l[idx] = f2bf(v - bf2f(h));
    }
    if (e >= ETOT) return;
    int d = (e < N_EDGES) ? ei[N_EDGES + e] : (e - N_EDGES);
    atomicAdd(&deg[d], 1);
}

// 3-phase grid-wide exclusive scan of deg[N_NODES] -> off[N_NODES+1]
__global__ void scan1_kernel(const int* __restrict__ deg, int* __restrict__ part) {
    __shared__ int sh[256];
    int t = threadIdx.x;
    int i = blockIdx.x * 256 + t;
    sh[t] = (i < N_NODES) ? deg[i] : 0;
    __syncthreads();
    #pragma unroll
    for (int o = 128; o; o >>= 1) {
        if (t < o) sh[t] += sh[t + o];
        __syncthreads();
    }
    if (t == 0) part[blockIdx.x] = sh[0];
}

__global__ void scan2_kernel(int* __restrict__ part, int* __restrict__ off) {
    __shared__ int sh[256];
    int t = threadIdx.x;
    int v = (t < SCAN_NBLK) ? part[t] : 0;
    sh[t] = v;
    __syncthreads();
    #pragma unroll
    for (int o = 1; o < 256; o <<= 1) {
        int u = (t >= o) ? sh[t - o] : 0;
        __syncthreads();
        sh[t] += u;
        __syncthreads();
    }
    if (t < SCAN_NBLK) part[t] = sh[t] - v;       // exclusive block base
    if (t == 255) off[N_NODES] = sh[255];
}

__global__ void scan3_kernel(int* __restrict__ deg, const int* __restrict__ part,
                             int* __restrict__ off) {
    __shared__ int sh[256];
    int t = threadIdx.x;
    int i = blockIdx.x * 256 + t;
    int v = (i < N_NODES) ? deg[i] : 0;
    sh[t] = v;
    __syncthreads();
    #pragma unroll
    for (int o = 1; o < 256; o <<= 1) {
        int u = (t >= o) ? sh[t - o] : 0;
        __syncthreads();
        sh[t] += u;
        __syncthreads();
    }
    if (i < N_NODES) {
        off[i] = part[blockIdx.x] + sh[t] - v;
        deg[i] = 0;                                // reuse as cursor
    }
}

__global__ void scatter_kernel(const int* __restrict__ ei, const int* __restrict__ off,
                               int* __restrict__ cursor, int* __restrict__ esrc) {
    int e = blockIdx.x * 256 + threadIdx.x;
    if (e >= ETOT) return;
    int s, d;
    if (e < N_EDGES) { s = ei[e]; d = ei[N_EDGES + e]; }
    else             { s = d = e - N_EDGES; }
    int pos = off[d] + atomicAdd(&cursor[d], 1);
    esrc[pos] = s;
}

// ---------------- LDS-free-A 2-product bf16 MFMA GEMM + fused alpha (layer 1) --------
template <int K>
__global__ __launch_bounds__(256) void gemm_mfma(const float* __restrict__ Af32,
                                                 const unsigned short* __restrict__ Wfh,
                                                 const unsigned short* __restrict__ Wfl,
                                                 const float* __restrict__ a_s,
                                                 const float* __restrict__ a_d,
                                                 unsigned short* __restrict__ Cb,
                                                 float* __restrict__ asrcO,
                                                 float* __restrict__ adstO,
                                                 int M) {
    __shared__ float smc[32][260];   // C staging
    int t  = threadIdx.x;
    int m0 = blockIdx.x * 64;
    int w  = t >> 6, l = t & 63;
    int lr = l & 15, lk = (l >> 4) * 8;

    float asv[4], adv[4];
    #pragma unroll
    for (int nf = 0; nf < 4; ++nf) {
        asv[nf] = a_s[w * 64 + nf * 16 + lr];
        adv[nf] = a_d[w * 64 + nf * 16 + lr];
    }

    float4v acc[4][4];
    #pragma unroll
    for (int mf = 0; mf < 4; ++mf)
        #pragma unroll
        for (int nf = 0; nf < 4; ++nf)
            acc[mf][nf] = (float4v){0.f, 0.f, 0.f, 0.f};

    constexpr int KB = K / 32;
    #pragma unroll 2
    for (int kb = 0; kb < KB; ++kb) {
        short8v b_hf[4], b_lf[4];
        #pragma unroll
        for (int nf = 0; nf < 4; ++nf) {
            size_t bidx = (size_t)((kb * 16 + w * 4 + nf) * 512 + l * 8);
            b_hf[nf] = *(const short8v*)&Wfh[bidx];
            b_lf[nf] = *(const short8v*)&Wfl[bidx];
        }
        short8v a_f[4];
        #pragma unroll
        for (int mf = 0; mf < 4; ++mf) {
            int gr = m0 + mf * 16 + lr;
            float4 v0 = make_float4(0.f, 0.f, 0.f, 0.f), v1 = v0;
            if (gr < M) {
                const float* ap = &Af32[(size_t)gr * K + kb * 32 + lk];
                v0 = *(const float4*)ap;
                v1 = *(const float4*)(ap + 4);
            }
            short8v a;
            a[0] = (short)f2bf(v0.x); a[1] = (short)f2bf(v0.y);
            a[2] = (short)f2bf(v0.z); a[3] = (short)f2bf(v0.w);
            a[4] = (short)f2bf(v1.x); a[5] = (short)f2bf(v1.y);
            a[6] = (short)f2bf(v1.z); a[7] = (short)f2bf(v1.w);
            a_f[mf] = a;
        }
        #pragma unroll
        for (int mf = 0; mf < 4; ++mf)
            #pragma unroll
            for (int nf = 0; nf < 4; ++nf) {
                acc[mf][nf] = __builtin_amdgcn_mfma_f32_16x16x32_bf16(a_f[mf], b_hf[nf], acc[mf][nf], 0, 0, 0);
                acc[mf][nf] = __builtin_amdgcn_mfma_f32_16x16x32_bf16(a_f[mf], b_lf[nf], acc[mf][nf], 0, 0, 0);
            }
    }

    // fused alpha (head w), 16-lane reduce
    #pragma unroll
    for (int mf = 0; mf < 4; ++mf)
        #pragma unroll
        for (int r = 0; r < 4; ++r) {
            float ps = acc[mf][0][r] * asv[0] + acc[mf][1][r] * asv[1]
                     + acc[mf][2][r] * asv[2] + acc[mf][3][r] * asv[3];
            float pd = acc[mf][0][r] * adv[0] + acc[mf][1][r] * adv[1]
                     + acc[mf][2][r] * adv[2] + acc[mf][3][r] * adv[3];
            #pragma unroll
            for (int o = 8; o; o >>= 1) {
                ps += __shfl_xor(ps, o);
                pd += __shfl_xor(pd, o);
            }
            int gr = m0 + mf * 16 + (l >> 4) * 4 + r;
            if (lr == 0 && gr < M) {
                asrcO[gr * 4 + w] = ps;
                adstO[gr * 4 + w] = pd;
            }
        }

    // C epilogue via LDS: two 32-row halves, coalesced bf16 stores
    #pragma unroll
    for (int half = 0; half < 2; ++half) {
        __syncthreads();
        #pragma unroll
        for (int mf2 = 0; mf2 < 2; ++mf2) {
            int mf = half * 2 + mf2;
            #pragma unroll
            for (int nf = 0; nf < 4; ++nf)
                #pragma unroll
                for (int r = 0; r < 4; ++r)
                    smc[mf2 * 16 + (l >> 4) * 4 + r][w * 64 + nf * 16 + lr] = acc[mf][nf][r];
        }
        __syncthreads();
        #pragma unroll
        for (int p = 0; p < 8; ++p) {
            int idx = t + p * 256;
            int row = idx >> 6, c4 = (idx & 63) * 4;
            int gr = m0 + half * 32 + row;
            if (gr < M) {
                float4 v = *(const float4*)&smc[row][c4];
                ushort4 hv;
                hv.x = f2bf(v.x); hv.y = f2bf(v.y); hv.z = f2bf(v.z); hv.w = f2bf(v.w);
                *(ushort4*)&Cb[(size_t)gr * F1 + c4] = hv;
            }
        }
    }
}

// ------- FUSED: agg1 (segment softmax+aggregate) + in-block gemm2 + alpha2 -----------
// Block = 16 dst nodes, 4 waves; wave wv handles nodes nb+wv*4..+3 (gather phase,
// wave-local LDS sync only). Then one __syncthreads and an M=16 MFMA gemm2 against
// fragment-linear W2 (L2-hot), fused alpha2, LDS-staged coalesced bf16 C write.
__global__ __launch_bounds__(256) void agg1g2_kernel(
        const unsigned short* __restrict__ hb,     // h1 bf16 [N][256]
        const float* __restrict__ asrc, const float* __restrict__ adst,
        const int* __restrict__ off, const int* __restrict__ esrc,
        const float* __restrict__ b1,
        const unsigned short* __restrict__ W2h, const unsigned short* __restrict__ W2l,
        const float* __restrict__ as2, const float* __restrict__ ad2,
        unsigned short* __restrict__ h2b,          // out bf16 [N][256]
        float* __restrict__ asrc2, float* __restrict__ adst2) {
    __shared__ unsigned short outT[16][264];   // layer-1 out tile bf16 (+8 pad)
    __shared__ float smc[16][260];             // C staging
    __shared__ int   soff[4][64];
    __shared__ float cf[4][64][4];
    int t  = threadIdx.x;
    int wv = t >> 6, l = t & 63;
    int lr = l & 15, lk = (l >> 4) * 8;
    int hd = l >> 4;                            // this lane's head (gather phase)
    int nb = blockIdx.x * 16;
    const char* hbase = (const char*)hb;
    int lb = l * 8;

    // ---- gather phase: 4 nodes per wave, serial ----
    #pragma unroll
    for (int j = 0; j < 4; ++j) {
        int d  = nb + wv * 4 + j;
        int e0 = off[d], e1 = off[d + 1];
        float4 ad = *(const float4*)(adst + (size_t)d * 4);
        float den = 0.f, a0 = 0.f, a1 = 0.f, a2 = 0.f, a3 = 0.f;
        for (int base = e0; base < e1; base += 64) {
            int cnt = min(64, e1 - base);
            if (l < cnt) {
                int s = esrc[base + l];
                soff[wv][l] = s * (F1 * 2);
                float4 as = *(const float4*)(asrc + (size_t)s * 4);
                cf[wv][l][0] = __expf(lrelu(as.x + ad.x));
                cf[wv][l][1] = __expf(lrelu(as.y + ad.y));
                cf[wv][l][2] = __expf(lrelu(as.z + ad.z));
                cf[wv][l][3] = __expf(lrelu(as.w + ad.w));
            }
            wave_lds_fence();
            int i = 0;
            for (; i + 4 <= cnt; i += 4) {
                int o0 = soff[wv][i], o1 = soff[wv][i + 1];
                int o2 = soff[wv][i + 2], o3 = soff[wv][i + 3];
                ushort4 h0 = *(const ushort4*)(hbase + o0 + lb);
                ushort4 h1 = *(const ushort4*)(hbase + o1 + lb);
                ushort4 h2 = *(const ushort4*)(hbase + o2 + lb);
                ushort4 h3 = *(const ushort4*)(hbase + o3 + lb);
                float c0 = cf[wv][i][hd], c1 = cf[wv][i + 1][hd];
                float c2 = cf[wv][i + 2][hd], c3 = cf[wv][i + 3][hd];
                den += (c0 + c1) + (c2 + c3);
                a0 += c0 * bf2f(h0.x) + c1 * bf2f(h1.x) + c2 * bf2f(h2.x) + c3 * bf2f(h3.x);
                a1 += c0 * bf2f(h0.y) + c1 * bf2f(h1.y) + c2 * bf2f(h2.y) + c3 * bf2f(h3.y);
                a2 += c0 * bf2f(h0.z) + c1 * bf2f(h1.z) + c2 * bf2f(h2.z) + c3 * bf2f(h3.z);
                a3 += c0 * bf2f(h0.w) + c1 * bf2f(h1.w) + c2 * bf2f(h2.w) + c3 * bf2f(h3.w);
            }
            for (; i < cnt; ++i) {
                int o = soff[wv][i];
                float c = cf[wv][i][hd];
                ushort4 hv = *(const ushort4*)(hbase + o + lb);
                den += c;
                a0 += c * bf2f(hv.x);
                a1 += c * bf2f(hv.y);
                a2 += c * bf2f(hv.z);
                a3 += c * bf2f(hv.w);
            }
            wave_lds_fence();
        }
        float r = 1.f / fmaxf(den, 1e-16f);
        ushort4 hv;
        hv.x = f2bf(fmaxf(a0 * r + b1[l * 4 + 0], 0.f));
        hv.y = f2bf(fmaxf(a1 * r + b1[l * 4 + 1], 0.f));
        hv.z = f2bf(fmaxf(a2 * r + b1[l * 4 + 2], 0.f));
        hv.w = f2bf(fmaxf(a3 * r + b1[l * 4 + 3], 0.f));
        *(ushort4*)&outT[wv * 4 + j][l * 4] = hv;
    }
    __syncthreads();   // all 16 rows of outT ready

    // ---- in-block gemm2: h2[16,256] = outT[16,256] @ W2 (split hi/lo) ----
    float asv[4], adv[4];
    #pragma unroll
    for (int nf = 0; nf < 4; ++nf) {
        asv[nf] = as2[wv * 64 + nf * 16 + lr];
        adv[nf] = ad2[wv * 64 + nf * 16 + lr];
    }
    float4v acc[4];
    #pragma unroll
    for (int nf = 0; nf < 4; ++nf) acc[nf] = (float4v){0.f, 0.f, 0.f, 0.f};

    #pragma unroll
    for (int kb = 0; kb < 8; ++kb) {
        short8v a_f = *(short8v*)&outT[lr][kb * 32 + lk];
        #pragma unroll
        for (int nf = 0; nf < 4; ++nf) {
            size_t bidx = (size_t)((kb * 16 + wv * 4 + nf) * 512 + l * 8);
            short8v bh = *(const short8v*)&W2h[bidx];
            short8v bl = *(const short8v*)&W2l[bidx];
            acc[nf] = __builtin_amdgcn_mfma_f32_16x16x32_bf16(a_f, bh, acc[nf], 0, 0, 0);
            acc[nf] = __builtin_amdgcn_mfma_f32_16x16x32_bf16(a_f, bl, acc[nf], 0, 0, 0);
        }
    }

    // ---- fused alpha2 (head wv), 16-lane reduce ----
    #pragma unroll
    for (int r = 0; r < 4; ++r) {
        float ps = acc[0][r] * asv[0] + acc[1][r] * asv[1]
                 + acc[2][r] * asv[2] + acc[3][r] * asv[3];
        float pd = acc[0][r] * adv[0] + acc[1][r] * adv[1]
                 + acc[2][r] * adv[2] + acc[3][r] * adv[3];
        #pragma unroll
        for (int o = 8; o; o >>= 1) {
            ps += __shfl_xor(ps, o);
            pd += __shfl_xor(pd, o);
        }
        if (lr == 0) {
            int node = nb + (l >> 4) * 4 + r;
            asrc2[node * 4 + wv] = ps;
            adst2[node * 4 + wv] = pd;
        }
    }

    // ---- C write via LDS staging, coalesced bf16 ----
    __syncthreads();   // outT reads done
    #pragma unroll
    for (int nf = 0; nf < 4; ++nf)
        #pragma unroll
        for (int r = 0; r < 4; ++r)
            smc[(l >> 4) * 4 + r][wv * 64 + nf * 16 + lr] = acc[nf][r];
    __syncthreads();
    #pragma unroll
    for (int p = 0; p < 4; ++p) {
        int idx = t + p * 256;            // 0..1023: 16 rows x 64 ushort4 chunks
        int row = idx >> 6, c4 = (idx & 63) * 4;
        float4 v = *(const float4*)&smc[row][c4];
        ushort4 hv;
        hv.x = f2bf(v.x); hv.y = f2bf(v.y); hv.z = f2bf(v.z); hv.w = f2bf(v.w);
        *(ushort4*)&h2b[(size_t)(nb + row) * F1 + c4] = hv;
    }
}

// ---------------- layer-2 segment softmax + aggregation (one wave per dst node) -------
__global__ void agg2_kernel(const unsigned short* __restrict__ hb,
                            const float* __restrict__ asrc,
                            const float* __restrict__ adst,
                            const int* __restrict__ off,
                            const int* __restrict__ esrc,
                            const float* __restrict__ bias,
                            float* __restrict__ outF) {
    __shared__ int   soff[64];
    __shared__ float cf[64][4];
    int d    = blockIdx.x;
    int lane = threadIdx.x;  // 64 = 1 wave
    int w    = lane >> 4;
    int e0 = off[d], e1 = off[d + 1];
    float4 ad = *(const float4*)(adst + (size_t)d * 4);
    float den = 0.f;
    float a0 = 0.f, a1 = 0.f, a2 = 0.f, a3 = 0.f;
    const char* hbase = (const char*)hb;
    int lb = lane * 8;

    for (int base = e0; base < e1; base += 64) {
        int cnt = min(64, e1 - base);
        if (lane < cnt) {
            int s = esrc[base + lane];
            soff[lane] = s * (F1 * 2);
            float4 as = *(const float4*)(asrc + (size_t)s * 4);
            cf[lane][0] = __expf(lrelu(as.x + ad.x));
            cf[lane][1] = __expf(lrelu(as.y + ad.y));
            cf[lane][2] = __expf(lrelu(as.z + ad.z));
            cf[lane][3] = __expf(lrelu(as.w + ad.w));
        }
        __syncthreads();
        int i = 0;
        for (; i + 4 <= cnt; i += 4) {
            int o0 = soff[i], o1 = soff[i + 1], o2 = soff[i + 2], o3 = soff[i + 3];
            ushort4 h0 = *(const ushort4*)(hbase + o0 + lb);
            ushort4 h1 = *(const ushort4*)(hbase + o1 + lb);
            ushort4 h2 = *(const ushort4*)(hbase + o2 + lb);
            ushort4 h3 = *(const ushort4*)(hbase + o3 + lb);
            float c0 = cf[i][w], c1 = cf[i + 1][w], c2 = cf[i + 2][w], c3 = cf[i + 3][w];
            den += (c0 + c1) + (c2 + c3);
            a0 += c0 * bf2f(h0.x) + c1 * bf2f(h1.x) + c2 * bf2f(h2.x) + c3 * bf2f(h3.x);
            a1 += c0 * bf2f(h0.y) + c1 * bf2f(h1.y) + c2 * bf2f(h2.y) + c3 * bf2f(h3.y);
            a2 += c0 * bf2f(h0.z) + c1 * bf2f(h1.z) + c2 * bf2f(h2.z) + c3 * bf2f(h3.z);
            a3 += c0 * bf2f(h0.w) + c1 * bf2f(h1.w) + c2 * bf2f(h2.w) + c3 * bf2f(h3.w);
        }
        for (; i < cnt; ++i) {
            int o = soff[i];
            float c = cf[i][w];
            ushort4 hv = *(const ushort4*)(hbase + o + lb);
            den += c;
            a0 += c * bf2f(hv.x);
            a1 += c * bf2f(hv.y);
            a2 += c * bf2f(hv.z);
            a3 += c * bf2f(hv.w);
        }
        __syncthreads();
    }

    float r = 1.f / fmaxf(den, 1e-16f);
    float v0 = a0 * r, v1 = a1 * r, v2 = a2 * r, v3 = a3 * r;
    v0 += __shfl_xor(v0, 16); v0 += __shfl_xor(v0, 32);
    v1 += __shfl_xor(v1, 16); v1 += __shfl_xor(v1, 32);
    v2 += __shfl_xor(v2, 16); v2 += __shfl_xor(v2, 32);
    v3 += __shfl_xor(v3, 16); v3 += __shfl_xor(v3, 32);
    if (lane < 16) {
        float4 o;
        o.x = 0.25f * v0 + bias[lane * 4 + 0];
        o.y = 0.25f * v1 + bias[lane * 4 + 1];
        o.z = 0.25f * v2 + bias[lane * 4 + 2];
        o.w = 0.25f * v3 + bias[lane * 4 + 3];
        *(float4*)&outF[(size_t)d * HID + lane * 4] = o;
    }
}

// ---------------- fused global mean pool + graph MLP: one block per graph ----------------
__device__ __forceinline__ int lowerb(const int* __restrict__ a, int n, int v) {
    int lo = 0, hi = n;
    while (lo < hi) { int m = (lo + hi) >> 1; if (a[m] < v) lo = m + 1; else hi = m; }
    return lo;
}

__global__ void poolmlp_kernel(const float* __restrict__ h2,
                               const int* __restrict__ batch,
                               const float* __restrict__ Wm1, const float* __restrict__ bm1,
                               const float* __restrict__ Wm2, const float* __restrict__ bm2,
                               float* __restrict__ out) {
    __shared__ float sh[4][HID];
    int b = blockIdx.x;
    int t = threadIdx.x, w = t >> 6, c = t & 63;
    int lo = lowerb(batch, N_NODES, b);
    int hi = lowerb(batch, N_NODES, b + 1);
    float s = 0.f;
    for (int n = lo + w; n < hi; n += 4) s += h2[(size_t)n * HID + c];
    sh[w][c] = s;
    __syncthreads();
    if (w == 0) {
        float inv = 1.f / fmaxf((float)(hi - lo), 1.f);
        float P = (sh[0][c] + sh[1][c] + sh[2][c] + sh[3][c]) * inv;
        sh[0][c] = P;
        float s1 = bm1[c];
        #pragma unroll
        for (int k = 0; k < HID; ++k) s1 += sh[0][k] * Wm1[k * HID + c];
        float r = fmaxf(s1, 0.f) * Wm2[c];
        #pragma unroll
        for (int o = 32; o; o >>= 1) r += __shfl_xor(r, o);
        if (c == 0) out[b] = r + bm2[0];
    }
}

extern "C" void kernel_launch(void* const* d_in, const int* in_sizes, int n_in,
                              void* d_out, int out_size, void* d_ws, size_t ws_size,
                              hipStream_t stream) {
    const float* x   = (const float*)d_in[0];
    const int*   ei  = (const int*)d_in[1];
    const int*   bat = (const int*)d_in[2];
    const float* W1  = (const float*)d_in[3];
    const float* as1 = (const float*)d_in[4];
    const float* ad1 = (const float*)d_in[5];
    const float* b1  = (const float*)d_in[6];
    const float* W2  = (const float*)d_in[7];
    const float* as2 = (const float*)d_in[8];
    const float* ad2 = (const float*)d_in[9];
    const float* b2  = (const float*)d_in[10];
    const float* Wm1 = (const float*)d_in[11];
    const float* bm1 = (const float*)d_in[12];
    const float* Wm2 = (const float*)d_in[13];
    const float* bm2 = (const float*)d_in[14];
    float* out = (float*)d_out;

    char* ws = (char*)d_ws;
    size_t cursor = 0;
    auto alloc = [&](size_t bytes) {
        void* p = ws + cursor;
        cursor += (bytes + 511) & ~(size_t)511;
        return p;
    };
    int*   deg    = (int*)alloc((size_t)N_NODES * 4);
    int*   off    = (int*)alloc((size_t)(N_NODES + 1) * 4);
    int*   part   = (int*)alloc((size_t)SCAN_NBLK * 4);
    int*   esrc   = (int*)alloc((size_t)ETOT * 4);
    unsigned short* bufHb = (unsigned short*)alloc((size_t)N_NODES * F1 * 2); // h1 bf16
    unsigned short* h2b   = (unsigned short*)alloc((size_t)N_NODES * F1 * 2); // h2 bf16
    float* bufO   = (float*)alloc((size_t)N_NODES * HID * 4);                 // agg2 out
    float* asrc   = (float*)alloc((size_t)N_NODES * HEADS * 4);
    float* adst   = (float*)alloc((size_t)N_NODES * HEADS * 4);
    float* asrc2  = (float*)alloc((size_t)N_NODES * HEADS * 4);
    float* adst2  = (float*)alloc((size_t)N_NODES * HEADS * 4);
    unsigned short* W1th = (unsigned short*)alloc((size_t)256 * IN_C * 2);
    unsigned short* W1tl = (unsigned short*)alloc((size_t)256 * IN_C * 2);
    unsigned short* W2th = (unsigned short*)alloc((size_t)256 * F1 * 2);
    unsigned short* W2tl = (unsigned short*)alloc((size_t)256 * F1 * 2);

    hipMemsetAsync(deg, 0, (size_t)N_NODES * 4, stream);

    deg_kernel<<<(ETOT + 255) / 256, 256, 0, stream>>>(ei, deg, W1, W1th, W1tl,
                                                       W2, W2th, W2tl);
    scan1_kernel<<<SCAN_NBLK, 256, 0, stream>>>(deg, part);
    scan2_kernel<<<1, 256, 0, stream>>>(part, off);
    scan3_kernel<<<SCAN_NBLK, 256, 0, stream>>>(deg, part, off);
    scatter_kernel<<<(ETOT + 255) / 256, 256, 0, stream>>>(ei, off, deg, esrc);

    const int GB = (N_NODES + 63) / 64;
    // layer 1 GEMM (writes h1 bf16 + layer-1 alphas)
    gemm_mfma<IN_C><<<GB, 256, 0, stream>>>(x, W1th, W1tl, as1, ad1,
                                            bufHb, asrc, adst, N_NODES);
    // FUSED agg1 + gemm2 + alpha2 (writes h2 bf16 + layer-2 alphas)
    agg1g2_kernel<<<N_NODES / 16, 256, 0, stream>>>(bufHb, asrc, adst, off, esrc, b1,
                                                    W2th, W2tl, as2, ad2,
                                                    h2b, asrc2, adst2);
    // layer-2 aggregation (head-mean + bias)
    agg2_kernel<<<N_NODES, 64, 0, stream>>>(h2b, asrc2, adst2, off, esrc, b2, bufO);

    // fused pool + MLP
    poolmlp_kernel<<<NB, 256, 0, stream>>>(bufO, bat, Wm1, bm1, Wm2, bm2, out);
}

// Round 16
// 331.118 us; speedup vs baseline: 2.5857x; 1.0131x over previous
//
#include <hip/hip_runtime.h>
#include <hip/hip_bf16.h>

#define N_NODES 50000
#define N_EDGES 800000
#define ETOT    (N_EDGES + N_NODES)
#define NB      64
#define IN_C    128
#define HID     64
#define HEADS   4
#define F1      (HEADS * HID)   /* 256 */
#define NEG     0.2f
#define SCAN_NBLK ((N_NODES + 255) / 256)   /* 196 */
#define SCAT_NBLK ((ETOT + 255) / 256)      /* 3321 */
#define GB1       ((N_NODES + 63) / 64)     /* 782 */

typedef __attribute__((ext_vector_type(8))) short  short8v;
typedef __attribute__((ext_vector_type(4))) float  float4v;

__device__ __forceinline__ float lrelu(float x) { return x >= 0.f ? x : NEG * x; }

__device__ __forceinline__ unsigned short f2bf(float f) {
    unsigned u = __float_as_uint(f);
    u += 0x7FFFu + ((u >> 16) & 1u);
    return (unsigned short)(u >> 16);
}
__device__ __forceinline__ float bf2f(unsigned short h) {
    return __uint_as_float(((unsigned)h) << 16);
}

// wave-local LDS fence (intra-wave producer->consumer; no block barrier)
__device__ __forceinline__ void wave_lds_fence() {
    asm volatile("s_waitcnt lgkmcnt(0)" ::: "memory");
}

// fragment-linear W index: lane l of fragment (kb, ng) reads bytes [l*16, l*16+16)
__device__ __forceinline__ int wf_idx(int k, int n) {
    return (((k >> 5) * 16 + (n >> 4)) << 9) + (((k >> 3) & 3) << 7) + ((n & 15) << 3) + (k & 7);
}

// ---------------- CSR build: degree count + (fused) W conversion to fragment layout ----
__global__ void deg_kernel(const int* __restrict__ ei, int* __restrict__ deg,
                           const float* __restrict__ W1,
                           unsigned short* __restrict__ W1h, unsigned short* __restrict__ W1l,
                           const float* __restrict__ W2,
                           unsigned short* __restrict__ W2h, unsigned short* __restrict__ W2l) {
    int e = blockIdx.x * 256 + threadIdx.x;
    const int N1 = IN_C * 256;
    if (e < N1) {
        int k = e >> 8, n = e & 255;
        float v = W1[e];
        unsigned short h = f2bf(v);
        int idx = wf_idx(k, n);
        W1h[idx] = h;
        W1l[idx] = f2bf(v - bf2f(h));
    } else if (e < N1 + F1 * 256) {
        int j = e - N1;
        int k = j >> 8, n = j & 255;
        float v = W2[j];
        unsigned short h = f2bf(v);
        int idx = wf_idx(k, n);
        W2h[idx] = h;
        W2l[idx] = f2bf(v - bf2f(h));
    }
    if (e >= ETOT) return;
    int d = (e < N_EDGES) ? ei[N_EDGES + e] : (e - N_EDGES);
    atomicAdd(&deg[d], 1);
}

// 3-phase grid-wide exclusive scan of deg[N_NODES] -> off[N_NODES+1]
__global__ void scan1_kernel(const int* __restrict__ deg, int* __restrict__ part) {
    __shared__ int sh[256];
    int t = threadIdx.x;
    int i = blockIdx.x * 256 + t;
    sh[t] = (i < N_NODES) ? deg[i] : 0;
    __syncthreads();
    #pragma unroll
    for (int o = 128; o; o >>= 1) {
        if (t < o) sh[t] += sh[t + o];
        __syncthreads();
    }
    if (t == 0) part[blockIdx.x] = sh[0];
}

__global__ void scan2_kernel(int* __restrict__ part, int* __restrict__ off) {
    __shared__ int sh[256];
    int t = threadIdx.x;
    int v = (t < SCAN_NBLK) ? part[t] : 0;
    sh[t] = v;
    __syncthreads();
    #pragma unroll
    for (int o = 1; o < 256; o <<= 1) {
        int u = (t >= o) ? sh[t - o] : 0;
        __syncthreads();
        sh[t] += u;
        __syncthreads();
    }
    if (t < SCAN_NBLK) part[t] = sh[t] - v;       // exclusive block base
    if (t == 255) off[N_NODES] = sh[255];
}

__global__ void scan3_kernel(int* __restrict__ deg, const int* __restrict__ part,
                             int* __restrict__ off) {
    __shared__ int sh[256];
    int t = threadIdx.x;
    int i = blockIdx.x * 256 + t;
    int v = (i < N_NODES) ? deg[i] : 0;
    sh[t] = v;
    __syncthreads();
    #pragma unroll
    for (int o = 1; o < 256; o <<= 1) {
        int u = (t >= o) ? sh[t - o] : 0;
        __syncthreads();
        sh[t] += u;
        __syncthreads();
    }
    if (i < N_NODES) {
        off[i] = part[blockIdx.x] + sh[t] - v;
        deg[i] = 0;                                // reuse as cursor
    }
}

// ------- FUSED: layer-1 GEMM (blocks 0..GB1-1) + CSR scatter (blocks GB1..) ----------
// gemm1 is independent of off/esrc, so the scatter rides concurrently in the same
// dispatch (different pipes: gemm = MFMA/L2-latency, scatter = atomics/BW).
__global__ __launch_bounds__(256) void g1scat_kernel(
        const float* __restrict__ Af32,
        const unsigned short* __restrict__ Wfh, const unsigned short* __restrict__ Wfl,
        const float* __restrict__ a_s, const float* __restrict__ a_d,
        unsigned short* __restrict__ Cb,
        float* __restrict__ asrcO, float* __restrict__ adstO, int M,
        const int* __restrict__ ei, const int* __restrict__ off,
        int* __restrict__ cursor, int* __restrict__ esrc) {
    __shared__ float smc[32][260];   // C staging (gemm blocks only)
    int t = threadIdx.x;

    if (blockIdx.x >= GB1) {
        // ---- scatter part ----
        int e = (blockIdx.x - GB1) * 256 + t;
        if (e < ETOT) {
            int s, d;
            if (e < N_EDGES) { s = ei[e]; d = ei[N_EDGES + e]; }
            else             { s = d = e - N_EDGES; }
            int pos = off[d] + atomicAdd(&cursor[d], 1);
            esrc[pos] = s;
        }
        return;
    }

    // ---- gemm1 part (LDS-free A, fragment-linear W, LDS-staged C epilogue) ----
    constexpr int K = IN_C;
    int m0 = blockIdx.x * 64;
    int w  = t >> 6, l = t & 63;
    int lr = l & 15, lk = (l >> 4) * 8;

    float asv[4], adv[4];
    #pragma unroll
    for (int nf = 0; nf < 4; ++nf) {
        asv[nf] = a_s[w * 64 + nf * 16 + lr];
        adv[nf] = a_d[w * 64 + nf * 16 + lr];
    }

    float4v acc[4][4];
    #pragma unroll
    for (int mf = 0; mf < 4; ++mf)
        #pragma unroll
        for (int nf = 0; nf < 4; ++nf)
            acc[mf][nf] = (float4v){0.f, 0.f, 0.f, 0.f};

    constexpr int KB = K / 32;
    #pragma unroll 2
    for (int kb = 0; kb < KB; ++kb) {
        short8v b_hf[4], b_lf[4];
        #pragma unroll
        for (int nf = 0; nf < 4; ++nf) {
            size_t bidx = (size_t)((kb * 16 + w * 4 + nf) * 512 + l * 8);
            b_hf[nf] = *(const short8v*)&Wfh[bidx];
            b_lf[nf] = *(const short8v*)&Wfl[bidx];
        }
        short8v a_f[4];
        #pragma unroll
        for (int mf = 0; mf < 4; ++mf) {
            int gr = m0 + mf * 16 + lr;
            float4 v0 = make_float4(0.f, 0.f, 0.f, 0.f), v1 = v0;
            if (gr < M) {
                const float* ap = &Af32[(size_t)gr * K + kb * 32 + lk];
                v0 = *(const float4*)ap;
                v1 = *(const float4*)(ap + 4);
            }
            short8v a;
            a[0] = (short)f2bf(v0.x); a[1] = (short)f2bf(v0.y);
            a[2] = (short)f2bf(v0.z); a[3] = (short)f2bf(v0.w);
            a[4] = (short)f2bf(v1.x); a[5] = (short)f2bf(v1.y);
            a[6] = (short)f2bf(v1.z); a[7] = (short)f2bf(v1.w);
            a_f[mf] = a;
        }
        #pragma unroll
        for (int mf = 0; mf < 4; ++mf)
            #pragma unroll
            for (int nf = 0; nf < 4; ++nf) {
                acc[mf][nf] = __builtin_amdgcn_mfma_f32_16x16x32_bf16(a_f[mf], b_hf[nf], acc[mf][nf], 0, 0, 0);
                acc[mf][nf] = __builtin_amdgcn_mfma_f32_16x16x32_bf16(a_f[mf], b_lf[nf], acc[mf][nf], 0, 0, 0);
            }
    }

    // fused alpha (head w), 16-lane reduce
    #pragma unroll
    for (int mf = 0; mf < 4; ++mf)
        #pragma unroll
        for (int r = 0; r < 4; ++r) {
            float ps = acc[mf][0][r] * asv[0] + acc[mf][1][r] * asv[1]
                     + acc[mf][2][r] * asv[2] + acc[mf][3][r] * asv[3];
            float pd = acc[mf][0][r] * adv[0] + acc[mf][1][r] * adv[1]
                     + acc[mf][2][r] * adv[2] + acc[mf][3][r] * adv[3];
            #pragma unroll
            for (int o = 8; o; o >>= 1) {
                ps += __shfl_xor(ps, o);
                pd += __shfl_xor(pd, o);
            }
            int gr = m0 + mf * 16 + (l >> 4) * 4 + r;
            if (lr == 0 && gr < M) {
                asrcO[gr * 4 + w] = ps;
                adstO[gr * 4 + w] = pd;
            }
        }

    // C epilogue via LDS: two 32-row halves, coalesced bf16 stores
    #pragma unroll
    for (int half = 0; half < 2; ++half) {
        __syncthreads();
        #pragma unroll
        for (int mf2 = 0; mf2 < 2; ++mf2) {
            int mf = half * 2 + mf2;
            #pragma unroll
            for (int nf = 0; nf < 4; ++nf)
                #pragma unroll
                for (int r = 0; r < 4; ++r)
                    smc[mf2 * 16 + (l >> 4) * 4 + r][w * 64 + nf * 16 + lr] = acc[mf][nf][r];
        }
        __syncthreads();
        #pragma unroll
        for (int p = 0; p < 8; ++p) {
            int idx = t + p * 256;
            int row = idx >> 6, c4 = (idx & 63) * 4;
            int gr = m0 + half * 32 + row;
            if (gr < M) {
                float4 v = *(const float4*)&smc[row][c4];
                ushort4 hv;
                hv.x = f2bf(v.x); hv.y = f2bf(v.y); hv.z = f2bf(v.z); hv.w = f2bf(v.w);
                *(ushort4*)&Cb[(size_t)gr * F1 + c4] = hv;
            }
        }
    }
}

// ------- FUSED: agg1 (segment softmax+aggregate) + in-block gemm2 + alpha2 -----------
__global__ __launch_bounds__(256) void agg1g2_kernel(
        const unsigned short* __restrict__ hb,     // h1 bf16 [N][256]
        const float* __restrict__ asrc, const float* __restrict__ adst,
        const int* __restrict__ off, const int* __restrict__ esrc,
        const float* __restrict__ b1,
        const unsigned short* __restrict__ W2h, const unsigned short* __restrict__ W2l,
        const float* __restrict__ as2, const float* __restrict__ ad2,
        unsigned short* __restrict__ h2b,          // out bf16 [N][256]
        float* __restrict__ asrc2, float* __restrict__ adst2) {
    __shared__ unsigned short outT[16][264];   // layer-1 out tile bf16 (+8 pad)
    __shared__ float smc[16][260];             // C staging
    __shared__ int   soff[4][64];
    __shared__ float cf[4][64][4];
    int t  = threadIdx.x;
    int wv = t >> 6, l = t & 63;
    int lr = l & 15, lk = (l >> 4) * 8;
    int hd = l >> 4;
    int nb = blockIdx.x * 16;
    const char* hbase = (const char*)hb;
    int lb = l * 8;

    // ---- gather phase: 4 nodes per wave, serial ----
    #pragma unroll
    for (int j = 0; j < 4; ++j) {
        int d  = nb + wv * 4 + j;
        int e0 = off[d], e1 = off[d + 1];
        float4 ad = *(const float4*)(adst + (size_t)d * 4);
        float den = 0.f, a0 = 0.f, a1 = 0.f, a2 = 0.f, a3 = 0.f;
        for (int base = e0; base < e1; base += 64) {
            int cnt = min(64, e1 - base);
            if (l < cnt) {
                int s = esrc[base + l];
                soff[wv][l] = s * (F1 * 2);
                float4 as = *(const float4*)(asrc + (size_t)s * 4);
                cf[wv][l][0] = __expf(lrelu(as.x + ad.x));
                cf[wv][l][1] = __expf(lrelu(as.y + ad.y));
                cf[wv][l][2] = __expf(lrelu(as.z + ad.z));
                cf[wv][l][3] = __expf(lrelu(as.w + ad.w));
            }
            wave_lds_fence();
            int i = 0;
            for (; i + 4 <= cnt; i += 4) {
                int o0 = soff[wv][i], o1 = soff[wv][i + 1];
                int o2 = soff[wv][i + 2], o3 = soff[wv][i + 3];
                ushort4 h0 = *(const ushort4*)(hbase + o0 + lb);
                ushort4 h1 = *(const ushort4*)(hbase + o1 + lb);
                ushort4 h2 = *(const ushort4*)(hbase + o2 + lb);
                ushort4 h3 = *(const ushort4*)(hbase + o3 + lb);
                float c0 = cf[wv][i][hd], c1 = cf[wv][i + 1][hd];
                float c2 = cf[wv][i + 2][hd], c3 = cf[wv][i + 3][hd];
                den += (c0 + c1) + (c2 + c3);
                a0 += c0 * bf2f(h0.x) + c1 * bf2f(h1.x) + c2 * bf2f(h2.x) + c3 * bf2f(h3.x);
                a1 += c0 * bf2f(h0.y) + c1 * bf2f(h1.y) + c2 * bf2f(h2.y) + c3 * bf2f(h3.y);
                a2 += c0 * bf2f(h0.z) + c1 * bf2f(h1.z) + c2 * bf2f(h2.z) + c3 * bf2f(h3.z);
                a3 += c0 * bf2f(h0.w) + c1 * bf2f(h1.w) + c2 * bf2f(h2.w) + c3 * bf2f(h3.w);
            }
            for (; i < cnt; ++i) {
                int o = soff[wv][i];
                float c = cf[wv][i][hd];
                ushort4 hv = *(const ushort4*)(hbase + o + lb);
                den += c;
                a0 += c * bf2f(hv.x);
                a1 += c * bf2f(hv.y);
                a2 += c * bf2f(hv.z);
                a3 += c * bf2f(hv.w);
            }
            wave_lds_fence();
        }
        float r = 1.f / fmaxf(den, 1e-16f);
        ushort4 hv;
        hv.x = f2bf(fmaxf(a0 * r + b1[l * 4 + 0], 0.f));
        hv.y = f2bf(fmaxf(a1 * r + b1[l * 4 + 1], 0.f));
        hv.z = f2bf(fmaxf(a2 * r + b1[l * 4 + 2], 0.f));
        hv.w = f2bf(fmaxf(a3 * r + b1[l * 4 + 3], 0.f));
        *(ushort4*)&outT[wv * 4 + j][l * 4] = hv;
    }
    __syncthreads();

    // ---- in-block gemm2: h2[16,256] = outT[16,256] @ W2 (split hi/lo) ----
    float asv[4], adv[4];
    #pragma unroll
    for (int nf = 0; nf < 4; ++nf) {
        asv[nf] = as2[wv * 64 + nf * 16 + lr];
        adv[nf] = ad2[wv * 64 + nf * 16 + lr];
    }
    float4v acc[4];
    #pragma unroll
    for (int nf = 0; nf < 4; ++nf) acc[nf] = (float4v){0.f, 0.f, 0.f, 0.f};

    #pragma unroll
    for (int kb = 0; kb < 8; ++kb) {
        short8v a_f = *(short8v*)&outT[lr][kb * 32 + lk];
        #pragma unroll
        for (int nf = 0; nf < 4; ++nf) {
            size_t bidx = (size_t)((kb * 16 + wv * 4 + nf) * 512 + l * 8);
            short8v bh = *(const short8v*)&W2h[bidx];
            short8v bl = *(const short8v*)&W2l[bidx];
            acc[nf] = __builtin_amdgcn_mfma_f32_16x16x32_bf16(a_f, bh, acc[nf], 0, 0, 0);
            acc[nf] = __builtin_amdgcn_mfma_f32_16x16x32_bf16(a_f, bl, acc[nf], 0, 0, 0);
        }
    }

    // ---- fused alpha2 (head wv), 16-lane reduce ----
    #pragma unroll
    for (int r = 0; r < 4; ++r) {
        float ps = acc[0][r] * asv[0] + acc[1][r] * asv[1]
                 + acc[2][r] * asv[2] + acc[3][r] * asv[3];
        float pd = acc[0][r] * adv[0] + acc[1][r] * adv[1]
                 + acc[2][r] * adv[2] + acc[3][r] * adv[3];
        #pragma unroll
        for (int o = 8; o; o >>= 1) {
            ps += __shfl_xor(ps, o);
            pd += __shfl_xor(pd, o);
        }
        if (lr == 0) {
            int node = nb + (l >> 4) * 4 + r;
            asrc2[node * 4 + wv] = ps;
            adst2[node * 4 + wv] = pd;
        }
    }

    // ---- C write via LDS staging, coalesced bf16 ----
    __syncthreads();
    #pragma unroll
    for (int nf = 0; nf < 4; ++nf)
        #pragma unroll
        for (int r = 0; r < 4; ++r)
            smc[(l >> 4) * 4 + r][wv * 64 + nf * 16 + lr] = acc[nf][r];
    __syncthreads();
    #pragma unroll
    for (int p = 0; p < 4; ++p) {
        int idx = t + p * 256;
        int row = idx >> 6, c4 = (idx & 63) * 4;
        float4 v = *(const float4*)&smc[row][c4];
        ushort4 hv;
        hv.x = f2bf(v.x); hv.y = f2bf(v.y); hv.z = f2bf(v.z); hv.w = f2bf(v.w);
        *(ushort4*)&h2b[(size_t)(nb + row) * F1 + c4] = hv;
    }
}

// ---------------- layer-2 segment softmax + aggregation (one wave per dst node) -------
__global__ void agg2_kernel(const unsigned short* __restrict__ hb,
                            const float* __restrict__ asrc,
                            const float* __restrict__ adst,
                            const int* __restrict__ off,
                            const int* __restrict__ esrc,
                            const float* __restrict__ bias,
                            float* __restrict__ outF) {
    __shared__ int   soff[64];
    __shared__ float cf[64][4];
    int d    = blockIdx.x;
    int lane = threadIdx.x;  // 64 = 1 wave
    int w    = lane >> 4;
    int e0 = off[d], e1 = off[d + 1];
    float4 ad = *(const float4*)(adst + (size_t)d * 4);
    float den = 0.f;
    float a0 = 0.f, a1 = 0.f, a2 = 0.f, a3 = 0.f;
    const char* hbase = (const char*)hb;
    int lb = lane * 8;

    for (int base = e0; base < e1; base += 64) {
        int cnt = min(64, e1 - base);
        if (lane < cnt) {
            int s = esrc[base + lane];
            soff[lane] = s * (F1 * 2);
            float4 as = *(const float4*)(asrc + (size_t)s * 4);
            cf[lane][0] = __expf(lrelu(as.x + ad.x));
            cf[lane][1] = __expf(lrelu(as.y + ad.y));
            cf[lane][2] = __expf(lrelu(as.z + ad.z));
            cf[lane][3] = __expf(lrelu(as.w + ad.w));
        }
        __syncthreads();
        int i = 0;
        for (; i + 4 <= cnt; i += 4) {
            int o0 = soff[i], o1 = soff[i + 1], o2 = soff[i + 2], o3 = soff[i + 3];
            ushort4 h0 = *(const ushort4*)(hbase + o0 + lb);
            ushort4 h1 = *(const ushort4*)(hbase + o1 + lb);
            ushort4 h2 = *(const ushort4*)(hbase + o2 + lb);
            ushort4 h3 = *(const ushort4*)(hbase + o3 + lb);
            float c0 = cf[i][w], c1 = cf[i + 1][w], c2 = cf[i + 2][w], c3 = cf[i + 3][w];
            den += (c0 + c1) + (c2 + c3);
            a0 += c0 * bf2f(h0.x) + c1 * bf2f(h1.x) + c2 * bf2f(h2.x) + c3 * bf2f(h3.x);
            a1 += c0 * bf2f(h0.y) + c1 * bf2f(h1.y) + c2 * bf2f(h2.y) + c3 * bf2f(h3.y);
            a2 += c0 * bf2f(h0.z) + c1 * bf2f(h1.z) + c2 * bf2f(h2.z) + c3 * bf2f(h3.z);
            a3 += c0 * bf2f(h0.w) + c1 * bf2f(h1.w) + c2 * bf2f(h2.w) + c3 * bf2f(h3.w);
        }
        for (; i < cnt; ++i) {
            int o = soff[i];
            float c = cf[i][w];
            ushort4 hv = *(const ushort4*)(hbase + o + lb);
            den += c;
            a0 += c * bf2f(hv.x);
            a1 += c * bf2f(hv.y);
            a2 += c * bf2f(hv.z);
            a3 += c * bf2f(hv.w);
        }
        __syncthreads();
    }

    float r = 1.f / fmaxf(den, 1e-16f);
    float v0 = a0 * r, v1 = a1 * r, v2 = a2 * r, v3 = a3 * r;
    v0 += __shfl_xor(v0, 16); v0 += __shfl_xor(v0, 32);
    v1 += __shfl_xor(v1, 16); v1 += __shfl_xor(v1, 32);
    v2 += __shfl_xor(v2, 16); v2 += __shfl_xor(v2, 32);
    v3 += __shfl_xor(v3, 16); v3 += __shfl_xor(v3, 32);
    if (lane < 16) {
        float4 o;
        o.x = 0.25f * v0 + bias[lane * 4 + 0];
        o.y = 0.25f * v1 + bias[lane * 4 + 1];
        o.z = 0.25f * v2 + bias[lane * 4 + 2];
        o.w = 0.25f * v3 + bias[lane * 4 + 3];
        *(float4*)&outF[(size_t)d * HID + lane * 4] = o;
    }
}

// ---------------- fused global mean pool + graph MLP: one block per graph ----------------
__device__ __forceinline__ int lowerb(const int* __restrict__ a, int n, int v) {
    int lo = 0, hi = n;
    while (lo < hi) { int m = (lo + hi) >> 1; if (a[m] < v) lo = m + 1; else hi = m; }
    return lo;
}

__global__ void poolmlp_kernel(const float* __restrict__ h2,
                               const int* __restrict__ batch,
                               const float* __restrict__ Wm1, const float* __restrict__ bm1,
                               const float* __restrict__ Wm2, const float* __restrict__ bm2,
                               float* __restrict__ out) {
    __shared__ float sh[4][HID];
    int b = blockIdx.x;
    int t = threadIdx.x, w = t >> 6, c = t & 63;
    int lo = lowerb(batch, N_NODES, b);
    int hi = lowerb(batch, N_NODES, b + 1);
    float s = 0.f;
    for (int n = lo + w; n < hi; n += 4) s += h2[(size_t)n * HID + c];
    sh[w][c] = s;
    __syncthreads();
    if (w == 0) {
        float inv = 1.f / fmaxf((float)(hi - lo), 1.f);
        float P = (sh[0][c] + sh[1][c] + sh[2][c] + sh[3][c]) * inv;
        sh[0][c] = P;
        float s1 = bm1[c];
        #pragma unroll
        for (int k = 0; k < HID; ++k) s1 += sh[0][k] * Wm1[k * HID + c];
        float r = fmaxf(s1, 0.f) * Wm2[c];
        #pragma unroll
        for (int o = 32; o; o >>= 1) r += __shfl_xor(r, o);
        if (c == 0) out[b] = r + bm2[0];
    }
}

extern "C" void kernel_launch(void* const* d_in, const int* in_sizes, int n_in,
                              void* d_out, int out_size, void* d_ws, size_t ws_size,
                              hipStream_t stream) {
    const float* x   = (const float*)d_in[0];
    const int*   ei  = (const int*)d_in[1];
    const int*   bat = (const int*)d_in[2];
    const float* W1  = (const float*)d_in[3];
    const float* as1 = (const float*)d_in[4];
    const float* ad1 = (const float*)d_in[5];
    const float* b1  = (const float*)d_in[6];
    const float* W2  = (const float*)d_in[7];
    const float* as2 = (const float*)d_in[8];
    const float* ad2 = (const float*)d_in[9];
    const float* b2  = (const float*)d_in[10];
    const float* Wm1 = (const float*)d_in[11];
    const float* bm1 = (const float*)d_in[12];
    const float* Wm2 = (const float*)d_in[13];
    const float* bm2 = (const float*)d_in[14];
    float* out = (float*)d_out;

    char* ws = (char*)d_ws;
    size_t cursor = 0;
    auto alloc = [&](size_t bytes) {
        void* p = ws + cursor;
        cursor += (bytes + 511) & ~(size_t)511;
        return p;
    };
    int*   deg    = (int*)alloc((size_t)N_NODES * 4);
    int*   off    = (int*)alloc((size_t)(N_NODES + 1) * 4);
    int*   part   = (int*)alloc((size_t)SCAN_NBLK * 4);
    int*   esrc   = (int*)alloc((size_t)ETOT * 4);
    unsigned short* bufHb = (unsigned short*)alloc((size_t)N_NODES * F1 * 2); // h1 bf16
    unsigned short* h2b   = (unsigned short*)alloc((size_t)N_NODES * F1 * 2); // h2 bf16
    float* bufO   = (float*)alloc((size_t)N_NODES * HID * 4);                 // agg2 out
    float* asrc   = (float*)alloc((size_t)N_NODES * HEADS * 4);
    float* adst   = (float*)alloc((size_t)N_NODES * HEADS * 4);
    float* asrc2  = (float*)alloc((size_t)N_NODES * HEADS * 4);
    float* adst2  = (float*)alloc((size_t)N_NODES * HEADS * 4);
    unsigned short* W1th = (unsigned short*)alloc((size_t)256 * IN_C * 2);
    unsigned short* W1tl = (unsigned short*)alloc((size_t)256 * IN_C * 2);
    unsigned short* W2th = (unsigned short*)alloc((size_t)256 * F1 * 2);
    unsigned short* W2tl = (unsigned short*)alloc((size_t)256 * F1 * 2);

    hipMemsetAsync(deg, 0, (size_t)N_NODES * 4, stream);

    deg_kernel<<<(ETOT + 255) / 256, 256, 0, stream>>>(ei, deg, W1, W1th, W1tl,
                                                       W2, W2th, W2tl);
    scan1_kernel<<<SCAN_NBLK, 256, 0, stream>>>(deg, part);
    scan2_kernel<<<1, 256, 0, stream>>>(part, off);
    scan3_kernel<<<SCAN_NBLK, 256, 0, stream>>>(deg, part, off);

    // FUSED layer-1 GEMM + scatter (gemm independent of CSR; scatter rides along)
    g1scat_kernel<<<GB1 + SCAT_NBLK, 256, 0, stream>>>(
        x, W1th, W1tl, as1, ad1, bufHb, asrc, adst, N_NODES,
        ei, off, deg, esrc);

    // FUSED agg1 + gemm2 + alpha2
    agg1g2_kernel<<<N_NODES / 16, 256, 0, stream>>>(bufHb, asrc, adst, off, esrc, b1,
                                                    W2th, W2tl, as2, ad2,
                                                    h2b, asrc2, adst2);
    // layer-2 aggregation (head-mean + bias)
    agg2_kernel<<<N_NODES, 64, 0, stream>>>(h2b, asrc2, adst2, off, esrc, b2, bufO);

    // fused pool + MLP
    poolmlp_kernel<<<NB, 256, 0, stream>>>(bufO, bat, Wm1, bm1, Wm2, bm2, out);
}